// Round 8
// baseline (392.262 us; speedup 1.0000x reference)
//
#include <hip/hip_runtime.h>
#include <hip/hip_bf16.h>

// NT-Xent loss. N=4096 pairs, D=1024, 2N=8192 rows.
// loss = 1/T + mean_i log( sum_{j != i} exp(sim_ij - 1/T) ) - mean_i pos_i
// sim = Z Z^T (cosine); fixed max 1/T (cosine bound) -> no online max.
// R6: fp8 mfma_scale layout verified (absmax 0) but spilled ~70 regs.
// R7: launch_bounds cap raise -> NULL (VGPR pinned 128). Diagnosis: the
//     f8f6f4 scaled MFMA's C/D is not AGPR-allocated -> acc must live in
//     arch VGPRs -> demand must be cut, not the cap raised.
// R8: 256x128 cells, 8 waves (4Mx2N), per-wave 64x64: acc[2][2] f32x16
//     = 64 regs, frags 32, total ~120 < 128. LDS 3x24KB = 72KB ->
//     2 blocks/CU. Unmasked cells bj>=2bi+2: 992 = 2 clean rounds;
//     64 masked diag-band cells peeled to a small kernel.

#define NPAIR 4096
#define NROWS 8192
#define DIM   1024
#define NMAIN 992                   // cells (bi,bj128): bj >= 2bi+2
#define NKT   16                    // K-tiles of 64
#define INV_T 14.285714285714286f   // 1/0.07
#define SCL1  0x7F                  // E8M0 exponent 127 -> scale 2^0 = 1.0

typedef __attribute__((ext_vector_type(4)))  int   i32x4;
typedef __attribute__((ext_vector_type(8)))  int   i32x8;
typedef __attribute__((ext_vector_type(16))) float f32x16;

#define GLOAD_LDS16(g, l)                                              \
  __builtin_amdgcn_global_load_lds(                                    \
      (const __attribute__((address_space(1))) void*)(g),              \
      (__attribute__((address_space(3))) void*)(l), 16, 0, 0)

#define MFMA_FP8(A, B, C)                                              \
  __builtin_amdgcn_mfma_scale_f32_32x32x64_f8f6f4(                     \
      (A), (B), (C), 0, 0, 0, SCL1, 0, SCL1)

// ---------------------------------------------------------------------------
// Kernel A: per pair-row i: norms + cross dot (fp32); write fp8 e4m3
// normalized rows Z[i], Z[i+NPAIR]; pos[i] = cos/T; zero rowsum (2/block).
// ---------------------------------------------------------------------------
__global__ __launch_bounds__(256) void normalize_kernel(
    const float* __restrict__ l1, const float* __restrict__ l2,
    unsigned char* __restrict__ Z, float* __restrict__ pos,
    float* __restrict__ rowsum) {
  const int i = blockIdx.x;
  const int t = threadIdx.x;           // one float4 per thread
  if (t < 2) rowsum[i * 2 + t] = 0.f;
  const float4 a = ((const float4*)(l1 + (size_t)i * DIM))[t];
  const float4 b = ((const float4*)(l2 + (size_t)i * DIM))[t];
  float s1 = a.x*a.x + a.y*a.y + a.z*a.z + a.w*a.w;
  float s2 = b.x*b.x + b.y*b.y + b.z*b.z + b.w*b.w;
  float d  = a.x*b.x + a.y*b.y + a.z*b.z + a.w*b.w;

  #pragma unroll
  for (int off = 32; off; off >>= 1) {
    s1 += __shfl_down(s1, off);
    s2 += __shfl_down(s2, off);
    d  += __shfl_down(d,  off);
  }
  __shared__ float red[3][4];
  __shared__ float fin[3];
  const int wave = t >> 6, lane = t & 63;
  if (lane == 0) { red[0][wave] = s1; red[1][wave] = s2; red[2][wave] = d; }
  __syncthreads();
  if (t == 0) {
    float S1 = red[0][0] + red[0][1] + red[0][2] + red[0][3];
    float S2 = red[1][0] + red[1][1] + red[1][2] + red[1][3];
    float DD = red[2][0] + red[2][1] + red[2][2] + red[2][3];
    float r1 = rsqrtf(S1), r2 = rsqrtf(S2);
    fin[0] = r1; fin[1] = r2;
    pos[i] = DD * r1 * r2 * INV_T;
  }
  __syncthreads();
  const float r1 = fin[0], r2 = fin[1];
  int pa = __builtin_amdgcn_cvt_pk_fp8_f32(a.x * r1, a.y * r1, 0, false);
  pa     = __builtin_amdgcn_cvt_pk_fp8_f32(a.z * r1, a.w * r1, pa, true);
  int pb = __builtin_amdgcn_cvt_pk_fp8_f32(b.x * r2, b.y * r2, 0, false);
  pb     = __builtin_amdgcn_cvt_pk_fp8_f32(b.z * r2, b.w * r2, pb, true);
  ((int*)(Z + (size_t)i * DIM))[t] = pa;
  ((int*)(Z + (size_t)(i + NPAIR) * DIM))[t] = pb;
}

// ---------------------------------------------------------------------------
// Kernel B1: 992 fully-off-diagonal 256x128 cells (bj >= 2bi+2), fp8 MX.
// 8 waves (4Mx2N), per-wave 64x64 = 2x2 frags of 32x32 -> acc 64 VGPRs.
// LDS buf (24KB): A[256][64]@0, B[128][64]@16384; 3 bufs, 2-deep prefetch,
// counted vmcnt(3), 1 barrier/K-tile. Frag: row=lane&31, k=(lane>>5)*32+...
// LDS 16B-chunk XOR swizzle: phys = logical ^ (r&3) ^ ((r>>2)&3).
// ---------------------------------------------------------------------------
__global__ __launch_bounds__(512, 4) void ntxent_gemm_main(
    const unsigned char* __restrict__ Z, float* __restrict__ rowsum) {
  __shared__ unsigned char lds[3 * 24576];

  const int t    = threadIdx.x;
  const int wid  = t >> 6;
  const int lane = t & 63;
  const int l31  = lane & 31;
  const int hi   = lane >> 5;
  const int wm   = wid >> 1;        // 0..3: 64-row quarter of 256 rows
  const int wn   = wid & 1;         // 0..1: 64-col half of 128 cols

  // T1: bijective XCD swizzle (992 = 8*124), then decode.
  // C(bi) = bi*(63-bi) cells before row-block bi; bj = 2bi+2+rem.
  const int idx = (blockIdx.x & 7) * 124 + (blockIdx.x >> 3);
  int bi = (int)((63.0f - sqrtf(3969.0f - 4.0f * (float)idx)) * 0.5f);
  while ((bi + 1) * (62 - bi) <= idx) ++bi;
  while (bi * (63 - bi) > idx) --bi;
  const int bj = 2 * bi + 2 + (idx - bi * (63 - bi));
  const int brow = bi * 256, bcol = bj * 128;

  // Stage A tile 256x64 (16KB = 1024 chunks -> 2 gloads/thread).
  auto stageA = [&](int kt, int buf) {
    #pragma unroll
    for (int i = 0; i < 2; ++i) {
      const int cb = wid * 128 + i * 64;     // wave-uniform chunk base
      const int c  = cb + lane;
      const int r  = c >> 2;
      const int lc = (c & 3) ^ (r & 3) ^ ((r >> 2) & 3);
      GLOAD_LDS16(Z + (size_t)(brow + r) * DIM + kt * 64 + lc * 16,
                  lds + buf * 24576 + cb * 16);
    }
  };
  // Stage B tile 128x64 (8KB = 512 chunks -> 1 gload/thread).
  auto stageB = [&](int kt, int buf) {
    const int cb = wid * 64;
    const int c  = cb + lane;
    const int r  = c >> 2;
    const int lc = (c & 3) ^ (r & 3) ^ ((r >> 2) & 3);
    GLOAD_LDS16(Z + (size_t)(bcol + r) * DIM + kt * 64 + lc * 16,
                lds + buf * 24576 + 16384 + cb * 16);
  };
  // Read one lane's 32-byte fragment (row r, k = hi*32 + [0..31]).
  auto frag = [&](int buf, int opoff, int row) -> i32x8 {
    const unsigned char* base = lds + buf * 24576 + opoff + row * 64;
    const int swz = (row & 3) ^ ((row >> 2) & 3);
    const i32x4 lo = *(const i32x4*)(base + (((2 * hi)     ^ swz) << 4));
    const i32x4 hp = *(const i32x4*)(base + (((2 * hi + 1) ^ swz) << 4));
    i32x8 r8;
    r8[0] = lo[0]; r8[1] = lo[1]; r8[2] = lo[2]; r8[3] = lo[3];
    r8[4] = hp[0]; r8[5] = hp[1]; r8[6] = hp[2]; r8[7] = hp[3];
    return r8;
  };

  f32x16 acc[2][2];
  #pragma unroll
  for (int mi = 0; mi < 2; ++mi)
    #pragma unroll
    for (int ni = 0; ni < 2; ++ni)
      #pragma unroll
      for (int g = 0; g < 16; ++g) acc[mi][ni][g] = 0.f;

  // Prologue: stage tiles 0,1 (3 loads each); drain tile 0 -> vmcnt(3).
  stageA(0, 0); stageB(0, 0);
  stageA(1, 1); stageB(1, 1);
  asm volatile("s_waitcnt vmcnt(3)" ::: "memory");
  __builtin_amdgcn_s_barrier();

  int bcur = 0, bnext = 1, bfree = 2;
  for (int kt = 0; kt < NKT; ++kt) {
    i32x8 A0 = frag(bcur, 0,     wm * 64 + 0  + l31);
    i32x8 A1 = frag(bcur, 0,     wm * 64 + 32 + l31);
    i32x8 B0 = frag(bcur, 16384, wn * 64 + 0  + l31);
    i32x8 B1 = frag(bcur, 16384, wn * 64 + 32 + l31);
    if (kt + 2 < NKT) {                      // prefetch 2 ahead (3 loads)
      stageA(kt + 2, bfree);
      stageB(kt + 2, bfree);
    }
    asm volatile("s_waitcnt lgkmcnt(0)" ::: "memory");
    __builtin_amdgcn_sched_barrier(0);
    __builtin_amdgcn_s_setprio(1);
    acc[0][0] = MFMA_FP8(A0, B0, acc[0][0]);
    acc[0][1] = MFMA_FP8(A0, B1, acc[0][1]);
    acc[1][0] = MFMA_FP8(A1, B0, acc[1][0]);
    acc[1][1] = MFMA_FP8(A1, B1, acc[1][1]);
    __builtin_amdgcn_s_setprio(0);
    if (kt + 2 < NKT) {
      asm volatile("s_waitcnt vmcnt(3)" ::: "memory");   // tile kt+1 ready
    } else if (kt + 1 < NKT) {
      asm volatile("s_waitcnt vmcnt(0)" ::: "memory");   // last tile
    }
    __builtin_amdgcn_s_barrier();
    const int tmp = bcur; bcur = bnext; bnext = bfree; bfree = tmp;
  }

  // Epilogue. 32x32 C/D: col = lane&31, row = (g&3)+8*(g>>2)+4*hi.
  // Fully off-diag cell: every element is a strict pair, no mask.
  #pragma unroll
  for (int mi = 0; mi < 2; ++mi)
    #pragma unroll
    for (int ni = 0; ni < 2; ++ni)
      #pragma unroll
      for (int g = 0; g < 16; ++g)
        acc[mi][ni][g] = __expf((acc[mi][ni][g] - 1.0f) * INV_T);
  // Row sums: reduce across 32 cols; lanes l31==0 commit.
  #pragma unroll
  for (int mi = 0; mi < 2; ++mi)
    #pragma unroll
    for (int g = 0; g < 16; ++g) {
      float s = acc[mi][0][g] + acc[mi][1][g];
      s += __shfl_xor(s, 1);
      s += __shfl_xor(s, 2);
      s += __shfl_xor(s, 4);
      s += __shfl_xor(s, 8);
      s += __shfl_xor(s, 16);
      if (l31 == 0)
        atomicAdd(&rowsum[brow + wm * 64 + mi * 32 + (g & 3) + 8 * (g >> 2) + 4 * hi], s);
    }
  // Col sums: lane-local over mi,g; combine hi halves; lanes hi==0 commit.
  #pragma unroll
  for (int ni = 0; ni < 2; ++ni) {
    float cs = 0.f;
    #pragma unroll
    for (int mi = 0; mi < 2; ++mi)
      #pragma unroll
      for (int g = 0; g < 16; ++g) cs += acc[mi][ni][g];
    cs += __shfl_xor(cs, 32);
    if (hi == 0)
      atomicAdd(&rowsum[bcol + wn * 64 + ni * 32 + l31], cs);
  }
}

// ---------------------------------------------------------------------------
// Kernel B2: 64 diagonal-band 256x128 cells: d -> (bi = d>>1, bj = 2bi+(d&1)).
// Same pipeline; epilogue keeps only gcol > grow.
// ---------------------------------------------------------------------------
__global__ __launch_bounds__(512, 4) void ntxent_gemm_diag(
    const unsigned char* __restrict__ Z, float* __restrict__ rowsum) {
  __shared__ unsigned char lds[3 * 24576];

  const int t    = threadIdx.x;
  const int wid  = t >> 6;
  const int lane = t & 63;
  const int l31  = lane & 31;
  const int hi   = lane >> 5;
  const int wm   = wid >> 1;
  const int wn   = wid & 1;

  const int bi = blockIdx.x >> 1;
  const int bj = 2 * bi + (blockIdx.x & 1);
  const int brow = bi * 256, bcol = bj * 128;

  auto stageA = [&](int kt, int buf) {
    #pragma unroll
    for (int i = 0; i < 2; ++i) {
      const int cb = wid * 128 + i * 64;
      const int c  = cb + lane;
      const int r  = c >> 2;
      const int lc = (c & 3) ^ (r & 3) ^ ((r >> 2) & 3);
      GLOAD_LDS16(Z + (size_t)(brow + r) * DIM + kt * 64 + lc * 16,
                  lds + buf * 24576 + cb * 16);
    }
  };
  auto stageB = [&](int kt, int buf) {
    const int cb = wid * 64;
    const int c  = cb + lane;
    const int r  = c >> 2;
    const int lc = (c & 3) ^ (r & 3) ^ ((r >> 2) & 3);
    GLOAD_LDS16(Z + (size_t)(bcol + r) * DIM + kt * 64 + lc * 16,
                lds + buf * 24576 + 16384 + cb * 16);
  };
  auto frag = [&](int buf, int opoff, int row) -> i32x8 {
    const unsigned char* base = lds + buf * 24576 + opoff + row * 64;
    const int swz = (row & 3) ^ ((row >> 2) & 3);
    const i32x4 lo = *(const i32x4*)(base + (((2 * hi)     ^ swz) << 4));
    const i32x4 hp = *(const i32x4*)(base + (((2 * hi + 1) ^ swz) << 4));
    i32x8 r8;
    r8[0] = lo[0]; r8[1] = lo[1]; r8[2] = lo[2]; r8[3] = lo[3];
    r8[4] = hp[0]; r8[5] = hp[1]; r8[6] = hp[2]; r8[7] = hp[3];
    return r8;
  };

  f32x16 acc[2][2];
  #pragma unroll
  for (int mi = 0; mi < 2; ++mi)
    #pragma unroll
    for (int ni = 0; ni < 2; ++ni)
      #pragma unroll
      for (int g = 0; g < 16; ++g) acc[mi][ni][g] = 0.f;

  stageA(0, 0); stageB(0, 0);
  stageA(1, 1); stageB(1, 1);
  asm volatile("s_waitcnt vmcnt(3)" ::: "memory");
  __builtin_amdgcn_s_barrier();

  int bcur = 0, bnext = 1, bfree = 2;
  for (int kt = 0; kt < NKT; ++kt) {
    i32x8 A0 = frag(bcur, 0,     wm * 64 + 0  + l31);
    i32x8 A1 = frag(bcur, 0,     wm * 64 + 32 + l31);
    i32x8 B0 = frag(bcur, 16384, wn * 64 + 0  + l31);
    i32x8 B1 = frag(bcur, 16384, wn * 64 + 32 + l31);
    if (kt + 2 < NKT) {
      stageA(kt + 2, bfree);
      stageB(kt + 2, bfree);
    }
    asm volatile("s_waitcnt lgkmcnt(0)" ::: "memory");
    __builtin_amdgcn_sched_barrier(0);
    __builtin_amdgcn_s_setprio(1);
    acc[0][0] = MFMA_FP8(A0, B0, acc[0][0]);
    acc[0][1] = MFMA_FP8(A0, B1, acc[0][1]);
    acc[1][0] = MFMA_FP8(A1, B0, acc[1][0]);
    acc[1][1] = MFMA_FP8(A1, B1, acc[1][1]);
    __builtin_amdgcn_s_setprio(0);
    if (kt + 2 < NKT) {
      asm volatile("s_waitcnt vmcnt(3)" ::: "memory");
    } else if (kt + 1 < NKT) {
      asm volatile("s_waitcnt vmcnt(0)" ::: "memory");
    }
    __builtin_amdgcn_s_barrier();
    const int tmp = bcur; bcur = bnext; bnext = bfree; bfree = tmp;
  }

  // Keep only gcol > grow (each within-band strict pair exactly once).
  #pragma unroll
  for (int mi = 0; mi < 2; ++mi)
    #pragma unroll
    for (int ni = 0; ni < 2; ++ni) {
      const int gcol = bcol + wn * 64 + ni * 32 + l31;
      #pragma unroll
      for (int g = 0; g < 16; ++g) {
        const int grow = brow + wm * 64 + mi * 32 + (g & 3) + 8 * (g >> 2) + 4 * hi;
        const float v = acc[mi][ni][g];
        acc[mi][ni][g] = (gcol > grow) ? __expf((v - 1.0f) * INV_T) : 0.f;
      }
    }
  #pragma unroll
  for (int mi = 0; mi < 2; ++mi)
    #pragma unroll
    for (int g = 0; g < 16; ++g) {
      float s = acc[mi][0][g] + acc[mi][1][g];
      s += __shfl_xor(s, 1);
      s += __shfl_xor(s, 2);
      s += __shfl_xor(s, 4);
      s += __shfl_xor(s, 8);
      s += __shfl_xor(s, 16);
      if (l31 == 0)
        atomicAdd(&rowsum[brow + wm * 64 + mi * 32 + (g & 3) + 8 * (g >> 2) + 4 * hi], s);
    }
  #pragma unroll
  for (int ni = 0; ni < 2; ++ni) {
    float cs = 0.f;
    #pragma unroll
    for (int mi = 0; mi < 2; ++mi)
      #pragma unroll
      for (int g = 0; g < 16; ++g) cs += acc[mi][ni][g];
    cs += __shfl_xor(cs, 32);
    if (hi == 0)
      atomicAdd(&rowsum[bcol + wn * 64 + ni * 32 + l31], cs);
  }
}

// ---------------------------------------------------------------------------
// Kernel C: loss = 1/T + mean(log rowsum) - mean(pos)
// ---------------------------------------------------------------------------
__global__ __launch_bounds__(1024) void finalize_kernel(
    const float* __restrict__ rowsum, const float* __restrict__ pos,
    float* __restrict__ out) {
  const int t = threadIdx.x;
  float ls = 0.f, ps = 0.f;
  for (int i = t; i < NROWS; i += 1024) ls += logf(rowsum[i]);
  for (int i = t; i < NPAIR; i += 1024) ps += pos[i];
  #pragma unroll
  for (int off = 32; off; off >>= 1) {
    ls += __shfl_down(ls, off);
    ps += __shfl_down(ps, off);
  }
  __shared__ float sls[16], sps[16];
  const int wave = t >> 6, lane = t & 63;
  if (lane == 0) { sls[wave] = ls; sps[wave] = ps; }
  __syncthreads();
  if (t == 0) {
    float LS = 0.f, PS = 0.f;
    #pragma unroll
    for (int w = 0; w < 16; ++w) { LS += sls[w]; PS += sps[w]; }
    out[0] = INV_T + LS / (float)NROWS - PS / (float)NPAIR;
  }
}

extern "C" void kernel_launch(void* const* d_in, const int* in_sizes, int n_in,
                              void* d_out, int out_size, void* d_ws, size_t ws_size,
                              hipStream_t stream) {
  const float* l1 = (const float*)d_in[0];
  const float* l2 = (const float*)d_in[1];
  float* out = (float*)d_out;

  char* ws = (char*)d_ws;
  unsigned char* Z = (unsigned char*)ws;                   // 8 MB fp8
  float* rowsum = (float*)(ws + (size_t)NROWS * DIM);      // 32 KB
  float* pos    = rowsum + NROWS;                          // 16 KB

  normalize_kernel<<<NPAIR, 256, 0, stream>>>(l1, l2, Z, pos, rowsum);
  ntxent_gemm_main<<<NMAIN, 512, 0, stream>>>(Z, rowsum);
  ntxent_gemm_diag<<<64, 512, 0, stream>>>(Z, rowsum);
  finalize_kernel<<<1, 1024, 0, stream>>>(rowsum, pos, out);
}

// Round 9
// 125.004 us; speedup vs baseline: 3.1380x; 3.1380x over previous
//
#include <hip/hip_runtime.h>
#include <hip/hip_bf16.h>

// NT-Xent loss. N=4096 pairs, D=1024, 2N=8192 rows.
// loss = 1/T + mean_i log( sum_{j != i} exp(sim_ij - 1/T) ) - mean_i pos_i
// sim = Z Z^T (cosine); fixed max 1/T (cosine bound) -> no online max.
// R5 (verified, 111us): 496 off-diag 256^2 8-phase cells (2 clean rounds)
//     + 64 diag-band 128x256 cells; bf16; LDS-read + staging bound.
// R6-R8: mfma_scale f8f6f4 path spills structurally (C/D not AGPR-allocated
//     by the compiler; cap raise AND demand cut both null) -> abandoned.
// R9: R5 skeleton verbatim, dtype -> fp8 e4m3 via NON-scaled
//     mfma_f32_16x16x32_fp8_fp8 (bf16 rate, half the bytes; standard MFMA
//     class -> acc retires to AGPRs). ds_read_b64 frags, 64-B-row chunk
//     swizzle (^ r&3, optimal 4/bank), vmcnt recounted for 1-gload stages.

#define NPAIR 4096
#define NROWS 8192
#define DIM   1024
#define NOFF  496                   // strict off-diag 256^2 cells (32*31/2)
#define NITER 8                     // 16 K-tiles of 64, 2 per iteration
#define NKT   16                    // K-tiles of 64 (diag kernel)
#define INV_T 14.285714285714286f   // 1/0.07

typedef __attribute__((ext_vector_type(4))) float f32x4;

#define GLOAD_LDS16(g, l)                                              \
  __builtin_amdgcn_global_load_lds(                                    \
      (const __attribute__((address_space(1))) void*)(g),              \
      (__attribute__((address_space(3))) void*)(l), 16, 0, 0)

#define BAR()   __builtin_amdgcn_s_barrier()
#define WAITL() { asm volatile("s_waitcnt lgkmcnt(0)" ::: "memory");   \
                  __builtin_amdgcn_sched_barrier(0); }
#define WAIT_VM(N) asm volatile("s_waitcnt vmcnt(" #N ")" ::: "memory")

#define MFMA_FP8(A, B, C)                                              \
  __builtin_amdgcn_mfma_f32_16x16x32_fp8_fp8((long)(A), (long)(B), (C), 0, 0, 0)

// ---------------------------------------------------------------------------
// Kernel A: per pair-row i: norms + cross dot (fp32); write fp8 e4m3
// normalized rows Z[i], Z[i+NPAIR]; pos[i] = cos/T; zero rowsum (2/block).
// ---------------------------------------------------------------------------
__global__ __launch_bounds__(256) void normalize_kernel(
    const float* __restrict__ l1, const float* __restrict__ l2,
    unsigned char* __restrict__ Z, float* __restrict__ pos,
    float* __restrict__ rowsum) {
  const int i = blockIdx.x;
  const int t = threadIdx.x;           // one float4 per thread
  if (t < 2) rowsum[i * 2 + t] = 0.f;
  const float4 a = ((const float4*)(l1 + (size_t)i * DIM))[t];
  const float4 b = ((const float4*)(l2 + (size_t)i * DIM))[t];
  float s1 = a.x*a.x + a.y*a.y + a.z*a.z + a.w*a.w;
  float s2 = b.x*b.x + b.y*b.y + b.z*b.z + b.w*b.w;
  float d  = a.x*b.x + a.y*b.y + a.z*b.z + a.w*b.w;

  #pragma unroll
  for (int off = 32; off; off >>= 1) {
    s1 += __shfl_down(s1, off);
    s2 += __shfl_down(s2, off);
    d  += __shfl_down(d,  off);
  }
  __shared__ float red[3][4];
  __shared__ float fin[3];
  const int wave = t >> 6, lane = t & 63;
  if (lane == 0) { red[0][wave] = s1; red[1][wave] = s2; red[2][wave] = d; }
  __syncthreads();
  if (t == 0) {
    float S1 = red[0][0] + red[0][1] + red[0][2] + red[0][3];
    float S2 = red[1][0] + red[1][1] + red[1][2] + red[1][3];
    float DD = red[2][0] + red[2][1] + red[2][2] + red[2][3];
    float r1 = rsqrtf(S1), r2 = rsqrtf(S2);
    fin[0] = r1; fin[1] = r2;
    pos[i] = DD * r1 * r2 * INV_T;
  }
  __syncthreads();
  const float r1 = fin[0], r2 = fin[1];
  int pa = __builtin_amdgcn_cvt_pk_fp8_f32(a.x * r1, a.y * r1, 0, false);
  pa     = __builtin_amdgcn_cvt_pk_fp8_f32(a.z * r1, a.w * r1, pa, true);
  int pb = __builtin_amdgcn_cvt_pk_fp8_f32(b.x * r2, b.y * r2, 0, false);
  pb     = __builtin_amdgcn_cvt_pk_fp8_f32(b.z * r2, b.w * r2, pb, true);
  ((int*)(Z + (size_t)i * DIM))[t] = pa;
  ((int*)(Z + (size_t)(i + NPAIR) * DIM))[t] = pb;
}

// ---------------------------------------------------------------------------
// Kernel B1: 496 strict off-diagonal 256x256 cells (bi < bj), fp8, 8-phase.
// 8 half-slots of 128x64 fp8 (8 KB) = 64 KB LDS. Frag: row = lane&15,
// k = (lane>>4)*8 + [0..7] (K-contiguous, mirrors verified bf16 geometry).
// LDS rows are 64 B = 4 16B-chunks; swizzle chunk_phys = chunk ^ (r&3)
// (optimal 4 dword-accesses/bank for ds_read_b64).
// ---------------------------------------------------------------------------
__global__ __launch_bounds__(512, 2) void ntxent_gemm_offdiag(
    const unsigned char* __restrict__ Z, float* __restrict__ rowsum) {
  __shared__ unsigned char lds[8 * 8192];   // slot = buf*4 + op*2 + half

  const int t    = threadIdx.x;
  const int wid  = t >> 6;
  const int lane = t & 63;
  const int lrow = lane & 15;
  const int kgrp = lane >> 4;
  const int wm   = wid >> 2;        // 0..1  (M half)
  const int wn   = wid & 3;         // 0..3  (N quarter)
  const int bh   = wn >> 1;         // B half this wave reads
  const int brow0 = (wn & 1) * 64;  // row base within B half

  // T1: bijective XCD swizzle (496 = 8*62) + strict-upper decode (bi < bj).
  const int idx = (blockIdx.x & 7) * 62 + (blockIdx.x >> 3);
  int bj = (int)((1.0f + sqrtf(1.0f + 8.0f * (float)idx)) * 0.5f);
  while (bj * (bj - 1) / 2 > idx) --bj;
  while ((bj + 1) * bj / 2 <= idx) ++bj;
  const int bi = idx - bj * (bj - 1) / 2;
  const int brow = bi * 256, bcol = bj * 256;

#define SLOT(b, o, h) (lds + (((b) << 2 | (o) << 1 | (h)) * 8192))
  const unsigned char* As0 = SLOT(0, 0, wm);
  const unsigned char* As1 = SLOT(1, 0, wm);
  const unsigned char* Bs0 = SLOT(0, 1, bh);
  const unsigned char* Bs1 = SLOT(1, 1, bh);

  // Stage one 128x64 fp8 half-tile (512 chunks -> 1 gload/thread):
  // linear LDS dest, inverse chunk-swizzled global source.
  auto stage_half = [&](int rowbase, int kt, unsigned char* slotp) {
    const int cb = wid * 64;             // wave-uniform chunk base
    const int c  = cb + lane;
    const int r  = c >> 2;
    const int lc = (c & 3) ^ (r & 3);
    GLOAD_LDS16(Z + (size_t)(rowbase + r) * DIM + kt * 64 + lc * 16,
                slotp + cb * 16);
  };
  // Read 8 fp8 at (row, k = kk*32 + kgrp*8) with the chunk swizzle.
  auto ld8 = [&](const unsigned char* slotp, int row, int kk) -> long {
    const int cl = kk * 2 + (kgrp >> 1);
    return *(const long*)(slotp + row * 64 + ((cl ^ (row & 3)) << 4)
                          + (kgrp & 1) * 8);
  };

  long af[2][2], bfr[4][2];
  f32x4 acc[8][4];
  #pragma unroll
  for (int i = 0; i < 8; ++i)
    #pragma unroll
    for (int j = 0; j < 4; ++j) acc[i][j] = (f32x4){0.f, 0.f, 0.f, 0.f};

#define DSB(BS)                                                        \
  { _Pragma("unroll") for (int ni = 0; ni < 4; ++ni)                   \
    _Pragma("unroll") for (int kk = 0; kk < 2; ++kk)                   \
      bfr[ni][kk] = ld8((BS), brow0 + ni * 16 + lrow, kk); }
#define DSA(Q, AS)                                                     \
  { _Pragma("unroll") for (int e = 0; e < 2; ++e)                      \
    _Pragma("unroll") for (int kk = 0; kk < 2; ++kk)                   \
      af[e][kk] = ld8((AS), (2*(Q)+e) * 16 + lrow, kk); }
#define MM(Q)                                                          \
  { __builtin_amdgcn_s_setprio(1);                                     \
    _Pragma("unroll") for (int kk = 0; kk < 2; ++kk)                   \
    _Pragma("unroll") for (int e = 0; e < 2; ++e)                      \
    _Pragma("unroll") for (int ni = 0; ni < 4; ++ni)                   \
      acc[2*(Q)+e][ni] = MFMA_FP8(af[e][kk], bfr[ni][kk],              \
                                  acc[2*(Q)+e][ni]);                   \
    __builtin_amdgcn_s_setprio(0); }

  // Prologue: tile 0 (4 halves) + B halves of tile 1; full drain once.
  stage_half(brow,       0, SLOT(0, 0, 0));
  stage_half(brow + 128, 0, SLOT(0, 0, 1));
  stage_half(bcol,       0, SLOT(0, 1, 0));
  stage_half(bcol + 128, 0, SLOT(0, 1, 1));
  stage_half(bcol,       1, SLOT(1, 1, 0));
  stage_half(bcol + 128, 1, SLOT(1, 1, 1));
  asm volatile("s_waitcnt vmcnt(0)" ::: "memory");
  __syncthreads();

  for (int I = 0; I < NITER; ++I) {
    const int t0 = 2 * I, t1 = t0 + 1;
    const bool lastI = (I == NITER - 1);
    // ---- tile t0 (buf0) ----
    DSB(Bs0); DSA(0, As0);
    stage_half(brow,       t1, SLOT(1, 0, 0));
    BAR(); WAITL(); MM(0); BAR();
    DSA(1, As0);
    stage_half(brow + 128, t1, SLOT(1, 0, 1));
    BAR(); WAITL(); MM(1); BAR();
    DSA(2, As0);
    if (!lastI) stage_half(bcol,       t0 + 2, SLOT(0, 1, 0));
    BAR(); WAITL(); MM(2); BAR();
    DSA(3, As0);
    if (!lastI) stage_half(bcol + 128, t0 + 2, SLOT(0, 1, 1));
    BAR(); WAITL(); MM(3);
    if (lastI) { WAIT_VM(0); } else { WAIT_VM(2); }
    BAR();
    // ---- tile t1 (buf1) ----
    DSB(Bs1); DSA(0, As1);
    if (!lastI) stage_half(brow,       t0 + 2, SLOT(0, 0, 0));
    BAR(); WAITL(); MM(0); BAR();
    DSA(1, As1);
    if (!lastI) stage_half(brow + 128, t0 + 2, SLOT(0, 0, 1));
    BAR(); WAITL(); MM(1); BAR();
    DSA(2, As1);
    if (!lastI) stage_half(bcol,       t1 + 2, SLOT(1, 1, 0));
    BAR(); WAITL(); MM(2); BAR();
    DSA(3, As1);
    if (!lastI) stage_half(bcol + 128, t1 + 2, SLOT(1, 1, 1));
    BAR(); WAITL(); MM(3);
    if (!lastI) { WAIT_VM(2); }
    BAR();
  }

  // Epilogue. C/D layout (m89, dtype-independent): col = lane&15,
  // row = (lane>>4)*4 + j. Strict off-diag cell: no mask.
  #pragma unroll
  for (int mi = 0; mi < 8; ++mi)
    #pragma unroll
    for (int ni = 0; ni < 4; ++ni)
      #pragma unroll
      for (int j = 0; j < 4; ++j)
        acc[mi][ni][j] = __expf((acc[mi][ni][j] - 1.0f) * INV_T);
  // Row sums.
  #pragma unroll
  for (int mi = 0; mi < 8; ++mi) {
    float rs[4] = {0.f, 0.f, 0.f, 0.f};
    #pragma unroll
    for (int ni = 0; ni < 4; ++ni)
      #pragma unroll
      for (int j = 0; j < 4; ++j) rs[j] += acc[mi][ni][j];
    #pragma unroll
    for (int j = 0; j < 4; ++j) {
      float s = rs[j];
      s += __shfl_xor(s, 1);
      s += __shfl_xor(s, 2);
      s += __shfl_xor(s, 4);
      s += __shfl_xor(s, 8);
      if (lrow == 0)
        atomicAdd(&rowsum[brow + wm * 128 + mi * 16 + kgrp * 4 + j], s);
    }
  }
  // Col sums.
  #pragma unroll
  for (int ni = 0; ni < 4; ++ni) {
    float cs = 0.f;
    #pragma unroll
    for (int mi = 0; mi < 8; ++mi)
      cs += acc[mi][ni][0] + acc[mi][ni][1] + acc[mi][ni][2] + acc[mi][ni][3];
    cs += __shfl_xor(cs, 16);
    cs += __shfl_xor(cs, 32);
    if (kgrp == 0)
      atomicAdd(&rowsum[bcol + wn * 64 + ni * 16 + lrow], cs);
  }
}

// ---------------------------------------------------------------------------
// Kernel B2: diagonal band, fp8. 64 cells of 128x256; gcol > grow keeps each
// within-cell strict pair once. BK=64, 3 bufs x (A 8KB + B 16KB) = 72 KB,
// 2-deep prefetch, counted vmcnt(3), 1 barrier per K-tile.
// ---------------------------------------------------------------------------
__global__ __launch_bounds__(512, 2) void ntxent_gemm_diag(
    const unsigned char* __restrict__ Z, float* __restrict__ rowsum) {
  __shared__ unsigned char lds[3 * 24576];  // buf: A[128][64]@0, B[256][64]@8192

  const int t    = threadIdx.x;
  const int wid  = t >> 6;
  const int lane = t & 63;
  const int lrow = lane & 15;
  const int kgrp = lane >> 4;
  const int wm   = wid >> 2;        // 0..1: 64-row half of 128 rows
  const int wn   = wid & 3;         // 0..3: 64-col quarter of 256 cols

  const int d = blockIdx.x >> 1;
  const int arow0 = d * 256 + (blockIdx.x & 1) * 128;
  const int bcol0 = d * 256;

  auto stageA = [&](int kt, int buf) {       // 512 chunks -> 1 gload
    const int cb = wid * 64;
    const int c  = cb + lane;
    const int r  = c >> 2;
    const int lc = (c & 3) ^ (r & 3);
    GLOAD_LDS16(Z + (size_t)(arow0 + r) * DIM + kt * 64 + lc * 16,
                lds + buf * 24576 + cb * 16);
  };
  auto stageB = [&](int kt, int buf, int half) {   // 512 chunks each half
    const int cb = half * 512 + wid * 64;
    const int c  = cb + lane;
    const int r  = c >> 2;
    const int lc = (c & 3) ^ (r & 3);
    GLOAD_LDS16(Z + (size_t)(bcol0 + r) * DIM + kt * 64 + lc * 16,
                lds + buf * 24576 + 8192 + cb * 16);
  };
  auto ld8 = [&](int buf, int opoff, int row, int kk) -> long {
    const int cl = kk * 2 + (kgrp >> 1);
    return *(const long*)(lds + buf * 24576 + opoff + row * 64
                          + ((cl ^ (row & 3)) << 4) + (kgrp & 1) * 8);
  };

  f32x4 acc[4][4];
  #pragma unroll
  for (int i = 0; i < 4; ++i)
    #pragma unroll
    for (int j = 0; j < 4; ++j) acc[i][j] = (f32x4){0.f, 0.f, 0.f, 0.f};

  stageA(0, 0); stageB(0, 0, 0); stageB(0, 0, 1);
  stageA(1, 1); stageB(1, 1, 0); stageB(1, 1, 1);
  asm volatile("s_waitcnt vmcnt(3)" ::: "memory");
  __builtin_amdgcn_s_barrier();

  int bcur = 0, bnext = 1, bfree = 2;
  for (int kt = 0; kt < NKT; ++kt) {
    long a[4][2], b[4][2];
    #pragma unroll
    for (int mi = 0; mi < 4; ++mi)
      #pragma unroll
      for (int kk = 0; kk < 2; ++kk)
        a[mi][kk] = ld8(bcur, 0, wm * 64 + mi * 16 + lrow, kk);
    #pragma unroll
    for (int ni = 0; ni < 4; ++ni)
      #pragma unroll
      for (int kk = 0; kk < 2; ++kk)
        b[ni][kk] = ld8(bcur, 8192, wn * 64 + ni * 16 + lrow, kk);
    if (kt + 2 < NKT) {
      stageA(kt + 2, bfree);
      stageB(kt + 2, bfree, 0);
      stageB(kt + 2, bfree, 1);
    }
    asm volatile("s_waitcnt lgkmcnt(0)" ::: "memory");
    __builtin_amdgcn_sched_barrier(0);
    __builtin_amdgcn_s_setprio(1);
    #pragma unroll
    for (int kk = 0; kk < 2; ++kk)
      #pragma unroll
      for (int mi = 0; mi < 4; ++mi)
        #pragma unroll
        for (int ni = 0; ni < 4; ++ni)
          acc[mi][ni] = MFMA_FP8(a[mi][kk], b[ni][kk], acc[mi][ni]);
    __builtin_amdgcn_s_setprio(0);
    if (kt + 2 < NKT) {
      asm volatile("s_waitcnt vmcnt(3)" ::: "memory");
    } else if (kt + 1 < NKT) {
      asm volatile("s_waitcnt vmcnt(0)" ::: "memory");
    }
    __builtin_amdgcn_s_barrier();
    const int tmp = bcur; bcur = bnext; bnext = bfree; bfree = tmp;
  }

  // Keep only gcol > grow (each within-cell strict pair exactly once).
  #pragma unroll
  for (int mi = 0; mi < 4; ++mi)
    #pragma unroll
    for (int ni = 0; ni < 4; ++ni) {
      const int gcol = bcol0 + wn * 64 + ni * 16 + lrow;
      #pragma unroll
      for (int j = 0; j < 4; ++j) {
        const int grow = arow0 + wm * 64 + mi * 16 + kgrp * 4 + j;
        const float v = acc[mi][ni][j];
        acc[mi][ni][j] = (gcol > grow) ? __expf((v - 1.0f) * INV_T) : 0.f;
      }
    }
  #pragma unroll
  for (int mi = 0; mi < 4; ++mi) {
    float rs[4] = {0.f, 0.f, 0.f, 0.f};
    #pragma unroll
    for (int ni = 0; ni < 4; ++ni)
      #pragma unroll
      for (int j = 0; j < 4; ++j) rs[j] += acc[mi][ni][j];
    #pragma unroll
    for (int j = 0; j < 4; ++j) {
      float s = rs[j];
      s += __shfl_xor(s, 1);
      s += __shfl_xor(s, 2);
      s += __shfl_xor(s, 4);
      s += __shfl_xor(s, 8);
      if (lrow == 0)
        atomicAdd(&rowsum[arow0 + wm * 64 + mi * 16 + kgrp * 4 + j], s);
    }
  }
  #pragma unroll
  for (int ni = 0; ni < 4; ++ni) {
    float cs = 0.f;
    #pragma unroll
    for (int mi = 0; mi < 4; ++mi)
      cs += acc[mi][ni][0] + acc[mi][ni][1] + acc[mi][ni][2] + acc[mi][ni][3];
    cs += __shfl_xor(cs, 16);
    cs += __shfl_xor(cs, 32);
    if (kgrp == 0)
      atomicAdd(&rowsum[bcol0 + wn * 64 + ni * 16 + lrow], cs);
  }
}

// ---------------------------------------------------------------------------
// Kernel C: loss = 1/T + mean(log rowsum) - mean(pos)
// ---------------------------------------------------------------------------
__global__ __launch_bounds__(1024) void finalize_kernel(
    const float* __restrict__ rowsum, const float* __restrict__ pos,
    float* __restrict__ out) {
  const int t = threadIdx.x;
  float ls = 0.f, ps = 0.f;
  for (int i = t; i < NROWS; i += 1024) ls += logf(rowsum[i]);
  for (int i = t; i < NPAIR; i += 1024) ps += pos[i];
  #pragma unroll
  for (int off = 32; off; off >>= 1) {
    ls += __shfl_down(ls, off);
    ps += __shfl_down(ps, off);
  }
  __shared__ float sls[16], sps[16];
  const int wave = t >> 6, lane = t & 63;
  if (lane == 0) { sls[wave] = ls; sps[wave] = ps; }
  __syncthreads();
  if (t == 0) {
    float LS = 0.f, PS = 0.f;
    #pragma unroll
    for (int w = 0; w < 16; ++w) { LS += sls[w]; PS += sps[w]; }
    out[0] = INV_T + LS / (float)NROWS - PS / (float)NPAIR;
  }
}

extern "C" void kernel_launch(void* const* d_in, const int* in_sizes, int n_in,
                              void* d_out, int out_size, void* d_ws, size_t ws_size,
                              hipStream_t stream) {
  const float* l1 = (const float*)d_in[0];
  const float* l2 = (const float*)d_in[1];
  float* out = (float*)d_out;

  char* ws = (char*)d_ws;
  unsigned char* Z = (unsigned char*)ws;                   // 8 MB fp8
  float* rowsum = (float*)(ws + (size_t)NROWS * DIM);      // 32 KB
  float* pos    = rowsum + NROWS;                          // 16 KB

  normalize_kernel<<<NPAIR, 256, 0, stream>>>(l1, l2, Z, pos, rowsum);
  ntxent_gemm_offdiag<<<NOFF, 512, 0, stream>>>(Z, rowsum);
  ntxent_gemm_diag<<<64, 512, 0, stream>>>(Z, rowsum);
  finalize_kernel<<<1, 1024, 0, stream>>>(rowsum, pos, out);
}

// Round 10
// 103.305 us; speedup vs baseline: 3.7971x; 1.2100x over previous
//
#include <hip/hip_runtime.h>
#include <hip/hip_bf16.h>

// NT-Xent loss. N=4096 pairs, D=1024, 2N=8192 rows.
// loss = 1/T + mean_i log( sum_{j != i} exp(sim_ij - 1/T) ) - mean_i pos_i
// sim = Z Z^T (cosine); fixed max 1/T (cosine bound) -> no online max.
// R5 (bf16, verified): 496 off-diag 256^2 8-phase cells + 64 diag-band
//     cells = 111 us; LDS+barrier bound.
// R9 (fp8 non-scaled): acc in AGPRs (no spill), half the bytes -- but the
//     b64 swizzle (chunk ^ (r&3)) left a 4-way conflict inside each
//     16-lane group (kgrp const; even rows hit only 2 chunk slots):
//     SQ_LDS_BANK_CONFLICT 1.8e7, offdiag 88.9us > R5.
// R10: swizzle key -> (r>>1)&3 on BOTH stage-source and read (same
//     involution): rows of each parity spread over all 4 chunk slots,
//     2 rows/slot = 2-way = free. Everything else = R9 verbatim.

#define NPAIR 4096
#define NROWS 8192
#define DIM   1024
#define NOFF  496                   // strict off-diag 256^2 cells (32*31/2)
#define NITER 8                     // 16 K-tiles of 64, 2 per iteration
#define NKT   16                    // K-tiles of 64 (diag kernel)
#define INV_T 14.285714285714286f   // 1/0.07

typedef __attribute__((ext_vector_type(4))) float f32x4;

#define GLOAD_LDS16(g, l)                                              \
  __builtin_amdgcn_global_load_lds(                                    \
      (const __attribute__((address_space(1))) void*)(g),              \
      (__attribute__((address_space(3))) void*)(l), 16, 0, 0)

#define BAR()   __builtin_amdgcn_s_barrier()
#define WAITL() { asm volatile("s_waitcnt lgkmcnt(0)" ::: "memory");   \
                  __builtin_amdgcn_sched_barrier(0); }
#define WAIT_VM(N) asm volatile("s_waitcnt vmcnt(" #N ")" ::: "memory")

#define MFMA_FP8(A, B, C)                                              \
  __builtin_amdgcn_mfma_f32_16x16x32_fp8_fp8((long)(A), (long)(B), (C), 0, 0, 0)

// ---------------------------------------------------------------------------
// Kernel A: per pair-row i: norms + cross dot (fp32); write fp8 e4m3
// normalized rows Z[i], Z[i+NPAIR]; pos[i] = cos/T; zero rowsum (2/block).
// ---------------------------------------------------------------------------
__global__ __launch_bounds__(256) void normalize_kernel(
    const float* __restrict__ l1, const float* __restrict__ l2,
    unsigned char* __restrict__ Z, float* __restrict__ pos,
    float* __restrict__ rowsum) {
  const int i = blockIdx.x;
  const int t = threadIdx.x;           // one float4 per thread
  if (t < 2) rowsum[i * 2 + t] = 0.f;
  const float4 a = ((const float4*)(l1 + (size_t)i * DIM))[t];
  const float4 b = ((const float4*)(l2 + (size_t)i * DIM))[t];
  float s1 = a.x*a.x + a.y*a.y + a.z*a.z + a.w*a.w;
  float s2 = b.x*b.x + b.y*b.y + b.z*b.z + b.w*b.w;
  float d  = a.x*b.x + a.y*b.y + a.z*b.z + a.w*b.w;

  #pragma unroll
  for (int off = 32; off; off >>= 1) {
    s1 += __shfl_down(s1, off);
    s2 += __shfl_down(s2, off);
    d  += __shfl_down(d,  off);
  }
  __shared__ float red[3][4];
  __shared__ float fin[3];
  const int wave = t >> 6, lane = t & 63;
  if (lane == 0) { red[0][wave] = s1; red[1][wave] = s2; red[2][wave] = d; }
  __syncthreads();
  if (t == 0) {
    float S1 = red[0][0] + red[0][1] + red[0][2] + red[0][3];
    float S2 = red[1][0] + red[1][1] + red[1][2] + red[1][3];
    float DD = red[2][0] + red[2][1] + red[2][2] + red[2][3];
    float r1 = rsqrtf(S1), r2 = rsqrtf(S2);
    fin[0] = r1; fin[1] = r2;
    pos[i] = DD * r1 * r2 * INV_T;
  }
  __syncthreads();
  const float r1 = fin[0], r2 = fin[1];
  int pa = __builtin_amdgcn_cvt_pk_fp8_f32(a.x * r1, a.y * r1, 0, false);
  pa     = __builtin_amdgcn_cvt_pk_fp8_f32(a.z * r1, a.w * r1, pa, true);
  int pb = __builtin_amdgcn_cvt_pk_fp8_f32(b.x * r2, b.y * r2, 0, false);
  pb     = __builtin_amdgcn_cvt_pk_fp8_f32(b.z * r2, b.w * r2, pb, true);
  ((int*)(Z + (size_t)i * DIM))[t] = pa;
  ((int*)(Z + (size_t)(i + NPAIR) * DIM))[t] = pb;
}

// ---------------------------------------------------------------------------
// Kernel B1: 496 strict off-diagonal 256x256 cells (bi < bj), fp8, 8-phase.
// 8 half-slots of 128x64 fp8 (8 KB) = 64 KB LDS. Frag: row = lane&15,
// k = (lane>>4)*8 + [0..7]. LDS rows 64 B = 4 16B-chunks; swizzle
// chunk_phys = chunk ^ ((r>>1)&3): within each 16-lane group the 8 rows
// of one parity spread over all 4 chunk slots (2 rows each) = 2-way free.
// ---------------------------------------------------------------------------
__global__ __launch_bounds__(512, 2) void ntxent_gemm_offdiag(
    const unsigned char* __restrict__ Z, float* __restrict__ rowsum) {
  __shared__ unsigned char lds[8 * 8192];   // slot = buf*4 + op*2 + half

  const int t    = threadIdx.x;
  const int wid  = t >> 6;
  const int lane = t & 63;
  const int lrow = lane & 15;
  const int kgrp = lane >> 4;
  const int wm   = wid >> 2;        // 0..1  (M half)
  const int wn   = wid & 3;         // 0..3  (N quarter)
  const int bh   = wn >> 1;         // B half this wave reads
  const int brow0 = (wn & 1) * 64;  // row base within B half

  // T1: bijective XCD swizzle (496 = 8*62) + strict-upper decode (bi < bj).
  const int idx = (blockIdx.x & 7) * 62 + (blockIdx.x >> 3);
  int bj = (int)((1.0f + sqrtf(1.0f + 8.0f * (float)idx)) * 0.5f);
  while (bj * (bj - 1) / 2 > idx) --bj;
  while ((bj + 1) * bj / 2 <= idx) ++bj;
  const int bi = idx - bj * (bj - 1) / 2;
  const int brow = bi * 256, bcol = bj * 256;

#define SLOT(b, o, h) (lds + (((b) << 2 | (o) << 1 | (h)) * 8192))
  const unsigned char* As0 = SLOT(0, 0, wm);
  const unsigned char* As1 = SLOT(1, 0, wm);
  const unsigned char* Bs0 = SLOT(0, 1, bh);
  const unsigned char* Bs1 = SLOT(1, 1, bh);

  // Stage one 128x64 fp8 half-tile (512 chunks -> 1 gload/thread):
  // linear LDS dest, inverse chunk-swizzled global source.
  auto stage_half = [&](int rowbase, int kt, unsigned char* slotp) {
    const int cb = wid * 64;             // wave-uniform chunk base
    const int c  = cb + lane;
    const int r  = c >> 2;
    const int lc = (c & 3) ^ ((r >> 1) & 3);
    GLOAD_LDS16(Z + (size_t)(rowbase + r) * DIM + kt * 64 + lc * 16,
                slotp + cb * 16);
  };
  // Read 8 fp8 at (row, k = kk*32 + kgrp*8) with the chunk swizzle.
  auto ld8 = [&](const unsigned char* slotp, int row, int kk) -> long {
    const int cl = kk * 2 + (kgrp >> 1);
    return *(const long*)(slotp + row * 64 + ((cl ^ ((row >> 1) & 3)) << 4)
                          + (kgrp & 1) * 8);
  };

  long af[2][2], bfr[4][2];
  f32x4 acc[8][4];
  #pragma unroll
  for (int i = 0; i < 8; ++i)
    #pragma unroll
    for (int j = 0; j < 4; ++j) acc[i][j] = (f32x4){0.f, 0.f, 0.f, 0.f};

#define DSB(BS)                                                        \
  { _Pragma("unroll") for (int ni = 0; ni < 4; ++ni)                   \
    _Pragma("unroll") for (int kk = 0; kk < 2; ++kk)                   \
      bfr[ni][kk] = ld8((BS), brow0 + ni * 16 + lrow, kk); }
#define DSA(Q, AS)                                                     \
  { _Pragma("unroll") for (int e = 0; e < 2; ++e)                      \
    _Pragma("unroll") for (int kk = 0; kk < 2; ++kk)                   \
      af[e][kk] = ld8((AS), (2*(Q)+e) * 16 + lrow, kk); }
#define MM(Q)                                                          \
  { __builtin_amdgcn_s_setprio(1);                                     \
    _Pragma("unroll") for (int kk = 0; kk < 2; ++kk)                   \
    _Pragma("unroll") for (int e = 0; e < 2; ++e)                      \
    _Pragma("unroll") for (int ni = 0; ni < 4; ++ni)                   \
      acc[2*(Q)+e][ni] = MFMA_FP8(af[e][kk], bfr[ni][kk],              \
                                  acc[2*(Q)+e][ni]);                   \
    __builtin_amdgcn_s_setprio(0); }

  // Prologue: tile 0 (4 halves) + B halves of tile 1; full drain once.
  stage_half(brow,       0, SLOT(0, 0, 0));
  stage_half(brow + 128, 0, SLOT(0, 0, 1));
  stage_half(bcol,       0, SLOT(0, 1, 0));
  stage_half(bcol + 128, 0, SLOT(0, 1, 1));
  stage_half(bcol,       1, SLOT(1, 1, 0));
  stage_half(bcol + 128, 1, SLOT(1, 1, 1));
  asm volatile("s_waitcnt vmcnt(0)" ::: "memory");
  __syncthreads();

  for (int I = 0; I < NITER; ++I) {
    const int t0 = 2 * I, t1 = t0 + 1;
    const bool lastI = (I == NITER - 1);
    // ---- tile t0 (buf0) ----
    DSB(Bs0); DSA(0, As0);
    stage_half(brow,       t1, SLOT(1, 0, 0));
    BAR(); WAITL(); MM(0); BAR();
    DSA(1, As0);
    stage_half(brow + 128, t1, SLOT(1, 0, 1));
    BAR(); WAITL(); MM(1); BAR();
    DSA(2, As0);
    if (!lastI) stage_half(bcol,       t0 + 2, SLOT(0, 1, 0));
    BAR(); WAITL(); MM(2); BAR();
    DSA(3, As0);
    if (!lastI) stage_half(bcol + 128, t0 + 2, SLOT(0, 1, 1));
    BAR(); WAITL(); MM(3);
    if (lastI) { WAIT_VM(0); } else { WAIT_VM(2); }
    BAR();
    // ---- tile t1 (buf1) ----
    DSB(Bs1); DSA(0, As1);
    if (!lastI) stage_half(brow,       t0 + 2, SLOT(0, 0, 0));
    BAR(); WAITL(); MM(0); BAR();
    DSA(1, As1);
    if (!lastI) stage_half(brow + 128, t0 + 2, SLOT(0, 0, 1));
    BAR(); WAITL(); MM(1); BAR();
    DSA(2, As1);
    if (!lastI) stage_half(bcol,       t1 + 2, SLOT(1, 1, 0));
    BAR(); WAITL(); MM(2); BAR();
    DSA(3, As1);
    if (!lastI) stage_half(bcol + 128, t1 + 2, SLOT(1, 1, 1));
    BAR(); WAITL(); MM(3);
    if (!lastI) { WAIT_VM(2); }
    BAR();
  }

  // Epilogue. C/D layout (m89, dtype-independent): col = lane&15,
  // row = (lane>>4)*4 + j. Strict off-diag cell: no mask.
  #pragma unroll
  for (int mi = 0; mi < 8; ++mi)
    #pragma unroll
    for (int ni = 0; ni < 4; ++ni)
      #pragma unroll
      for (int j = 0; j < 4; ++j)
        acc[mi][ni][j] = __expf((acc[mi][ni][j] - 1.0f) * INV_T);
  // Row sums.
  #pragma unroll
  for (int mi = 0; mi < 8; ++mi) {
    float rs[4] = {0.f, 0.f, 0.f, 0.f};
    #pragma unroll
    for (int ni = 0; ni < 4; ++ni)
      #pragma unroll
      for (int j = 0; j < 4; ++j) rs[j] += acc[mi][ni][j];
    #pragma unroll
    for (int j = 0; j < 4; ++j) {
      float s = rs[j];
      s += __shfl_xor(s, 1);
      s += __shfl_xor(s, 2);
      s += __shfl_xor(s, 4);
      s += __shfl_xor(s, 8);
      if (lrow == 0)
        atomicAdd(&rowsum[brow + wm * 128 + mi * 16 + kgrp * 4 + j], s);
    }
  }
  // Col sums.
  #pragma unroll
  for (int ni = 0; ni < 4; ++ni) {
    float cs = 0.f;
    #pragma unroll
    for (int mi = 0; mi < 8; ++mi)
      cs += acc[mi][ni][0] + acc[mi][ni][1] + acc[mi][ni][2] + acc[mi][ni][3];
    cs += __shfl_xor(cs, 16);
    cs += __shfl_xor(cs, 32);
    if (kgrp == 0)
      atomicAdd(&rowsum[bcol + wn * 64 + ni * 16 + lrow], cs);
  }
}

// ---------------------------------------------------------------------------
// Kernel B2: diagonal band, fp8. 64 cells of 128x256; gcol > grow keeps each
// within-cell strict pair once. BK=64, 3 bufs x (A 8KB + B 16KB) = 72 KB,
// 2-deep prefetch, counted vmcnt(3), 1 barrier per K-tile.
// ---------------------------------------------------------------------------
__global__ __launch_bounds__(512, 2) void ntxent_gemm_diag(
    const unsigned char* __restrict__ Z, float* __restrict__ rowsum) {
  __shared__ unsigned char lds[3 * 24576];  // buf: A[128][64]@0, B[256][64]@8192

  const int t    = threadIdx.x;
  const int wid  = t >> 6;
  const int lane = t & 63;
  const int lrow = lane & 15;
  const int kgrp = lane >> 4;
  const int wm   = wid >> 2;        // 0..1: 64-row half of 128 rows
  const int wn   = wid & 3;         // 0..3: 64-col quarter of 256 cols

  const int d = blockIdx.x >> 1;
  const int arow0 = d * 256 + (blockIdx.x & 1) * 128;
  const int bcol0 = d * 256;

  auto stageA = [&](int kt, int buf) {       // 512 chunks -> 1 gload
    const int cb = wid * 64;
    const int c  = cb + lane;
    const int r  = c >> 2;
    const int lc = (c & 3) ^ ((r >> 1) & 3);
    GLOAD_LDS16(Z + (size_t)(arow0 + r) * DIM + kt * 64 + lc * 16,
                lds + buf * 24576 + cb * 16);
  };
  auto stageB = [&](int kt, int buf, int half) {   // 512 chunks each half
    const int cb = half * 512 + wid * 64;
    const int c  = cb + lane;
    const int r  = c >> 2;
    const int lc = (c & 3) ^ ((r >> 1) & 3);
    GLOAD_LDS16(Z + (size_t)(bcol0 + r) * DIM + kt * 64 + lc * 16,
                lds + buf * 24576 + 8192 + cb * 16);
  };
  auto ld8 = [&](int buf, int opoff, int row, int kk) -> long {
    const int cl = kk * 2 + (kgrp >> 1);
    return *(const long*)(lds + buf * 24576 + opoff + row * 64
                          + ((cl ^ ((row >> 1) & 3)) << 4) + (kgrp & 1) * 8);
  };

  f32x4 acc[4][4];
  #pragma unroll
  for (int i = 0; i < 4; ++i)
    #pragma unroll
    for (int j = 0; j < 4; ++j) acc[i][j] = (f32x4){0.f, 0.f, 0.f, 0.f};

  stageA(0, 0); stageB(0, 0, 0); stageB(0, 0, 1);
  stageA(1, 1); stageB(1, 1, 0); stageB(1, 1, 1);
  asm volatile("s_waitcnt vmcnt(3)" ::: "memory");
  __builtin_amdgcn_s_barrier();

  int bcur = 0, bnext = 1, bfree = 2;
  for (int kt = 0; kt < NKT; ++kt) {
    long a[4][2], b[4][2];
    #pragma unroll
    for (int mi = 0; mi < 4; ++mi)
      #pragma unroll
      for (int kk = 0; kk < 2; ++kk)
        a[mi][kk] = ld8(bcur, 0, wm * 64 + mi * 16 + lrow, kk);
    #pragma unroll
    for (int ni = 0; ni < 4; ++ni)
      #pragma unroll
      for (int kk = 0; kk < 2; ++kk)
        b[ni][kk] = ld8(bcur, 8192, wn * 64 + ni * 16 + lrow, kk);
    if (kt + 2 < NKT) {
      stageA(kt + 2, bfree);
      stageB(kt + 2, bfree, 0);
      stageB(kt + 2, bfree, 1);
    }
    asm volatile("s_waitcnt lgkmcnt(0)" ::: "memory");
    __builtin_amdgcn_sched_barrier(0);
    __builtin_amdgcn_s_setprio(1);
    #pragma unroll
    for (int kk = 0; kk < 2; ++kk)
      #pragma unroll
      for (int mi = 0; mi < 4; ++mi)
        #pragma unroll
        for (int ni = 0; ni < 4; ++ni)
          acc[mi][ni] = MFMA_FP8(a[mi][kk], b[ni][kk], acc[mi][ni]);
    __builtin_amdgcn_s_setprio(0);
    if (kt + 2 < NKT) {
      asm volatile("s_waitcnt vmcnt(3)" ::: "memory");
    } else if (kt + 1 < NKT) {
      asm volatile("s_waitcnt vmcnt(0)" ::: "memory");
    }
    __builtin_amdgcn_s_barrier();
    const int tmp = bcur; bcur = bnext; bnext = bfree; bfree = tmp;
  }

  // Keep only gcol > grow (each within-cell strict pair exactly once).
  #pragma unroll
  for (int mi = 0; mi < 4; ++mi)
    #pragma unroll
    for (int ni = 0; ni < 4; ++ni) {
      const int gcol = bcol0 + wn * 64 + ni * 16 + lrow;
      #pragma unroll
      for (int j = 0; j < 4; ++j) {
        const int grow = arow0 + wm * 64 + mi * 16 + kgrp * 4 + j;
        const float v = acc[mi][ni][j];
        acc[mi][ni][j] = (gcol > grow) ? __expf((v - 1.0f) * INV_T) : 0.f;
      }
    }
  #pragma unroll
  for (int mi = 0; mi < 4; ++mi) {
    float rs[4] = {0.f, 0.f, 0.f, 0.f};
    #pragma unroll
    for (int ni = 0; ni < 4; ++ni)
      #pragma unroll
      for (int j = 0; j < 4; ++j) rs[j] += acc[mi][ni][j];
    #pragma unroll
    for (int j = 0; j < 4; ++j) {
      float s = rs[j];
      s += __shfl_xor(s, 1);
      s += __shfl_xor(s, 2);
      s += __shfl_xor(s, 4);
      s += __shfl_xor(s, 8);
      if (lrow == 0)
        atomicAdd(&rowsum[arow0 + wm * 64 + mi * 16 + kgrp * 4 + j], s);
    }
  }
  #pragma unroll
  for (int ni = 0; ni < 4; ++ni) {
    float cs = 0.f;
    #pragma unroll
    for (int mi = 0; mi < 4; ++mi)
      cs += acc[mi][ni][0] + acc[mi][ni][1] + acc[mi][ni][2] + acc[mi][ni][3];
    cs += __shfl_xor(cs, 16);
    cs += __shfl_xor(cs, 32);
    if (kgrp == 0)
      atomicAdd(&rowsum[bcol0 + wn * 64 + ni * 16 + lrow], cs);
  }
}

// ---------------------------------------------------------------------------
// Kernel C: loss = 1/T + mean(log rowsum) - mean(pos)
// ---------------------------------------------------------------------------
__global__ __launch_bounds__(1024) void finalize_kernel(
    const float* __restrict__ rowsum, const float* __restrict__ pos,
    float* __restrict__ out) {
  const int t = threadIdx.x;
  float ls = 0.f, ps = 0.f;
  for (int i = t; i < NROWS; i += 1024) ls += logf(rowsum[i]);
  for (int i = t; i < NPAIR; i += 1024) ps += pos[i];
  #pragma unroll
  for (int off = 32; off; off >>= 1) {
    ls += __shfl_down(ls, off);
    ps += __shfl_down(ps, off);
  }
  __shared__ float sls[16], sps[16];
  const int wave = t >> 6, lane = t & 63;
  if (lane == 0) { sls[wave] = ls; sps[wave] = ps; }
  __syncthreads();
  if (t == 0) {
    float LS = 0.f, PS = 0.f;
    #pragma unroll
    for (int w = 0; w < 16; ++w) { LS += sls[w]; PS += sps[w]; }
    out[0] = INV_T + LS / (float)NROWS - PS / (float)NPAIR;
  }
}

extern "C" void kernel_launch(void* const* d_in, const int* in_sizes, int n_in,
                              void* d_out, int out_size, void* d_ws, size_t ws_size,
                              hipStream_t stream) {
  const float* l1 = (const float*)d_in[0];
  const float* l2 = (const float*)d_in[1];
  float* out = (float*)d_out;

  char* ws = (char*)d_ws;
  unsigned char* Z = (unsigned char*)ws;                   // 8 MB fp8
  float* rowsum = (float*)(ws + (size_t)NROWS * DIM);      // 32 KB
  float* pos    = rowsum + NROWS;                          // 16 KB

  normalize_kernel<<<NPAIR, 256, 0, stream>>>(l1, l2, Z, pos, rowsum);
  ntxent_gemm_offdiag<<<NOFF, 512, 0, stream>>>(Z, rowsum);
  ntxent_gemm_diag<<<64, 512, 0, stream>>>(Z, rowsum);
  finalize_kernel<<<1, 1024, 0, stream>>>(rowsum, pos, out);
}

// Round 11
// 102.780 us; speedup vs baseline: 3.8165x; 1.0051x over previous
//
#include <hip/hip_runtime.h>
#include <hip/hip_bf16.h>

// NT-Xent loss. N=4096 pairs, D=1024, 2N=8192 rows.
// loss = 1/T + mean_i log( sum_{j != i} exp(sim_ij - 1/T) ) - mean_i pos_i
// sim = Z Z^T (cosine); fixed max 1/T (cosine bound) -> no online max.
// R5:  496 off-diag 256^2 cells (2 clean rounds) + 64 diag-band cells.
// R9:  fp8 e4m3 non-scaled mfma (acc -> AGPRs, no spill), half the bytes.
// R10: fixed b64 swizzle key ((r>>1)&3 both sides) -> conflicts 1.8e7->6e6,
//      103 us total. Offdiag still 8-barrier/K-tile: sync-starved at fp8
//      (2484 MFMA cyc vs 5600 cyc/K-tile measured).
// R11: offdiag -> 3-buffer 1-barrier-per-K-tile pipeline (the structure
//      already verified in the diag kernel / R4): barriers 128->16/block,
//      lgkm waits 64->16. 24 ds_read_b64 + 4 gloads + 64 MFMA per K-tile.

#define NPAIR 4096
#define NROWS 8192
#define DIM   1024
#define NOFF  496                   // strict off-diag 256^2 cells (32*31/2)
#define NKT   16                    // K-tiles of 64
#define INV_T 14.285714285714286f   // 1/0.07

typedef __attribute__((ext_vector_type(4))) float f32x4;

#define GLOAD_LDS16(g, l)                                              \
  __builtin_amdgcn_global_load_lds(                                    \
      (const __attribute__((address_space(1))) void*)(g),              \
      (__attribute__((address_space(3))) void*)(l), 16, 0, 0)

#define MFMA_FP8(A, B, C)                                              \
  __builtin_amdgcn_mfma_f32_16x16x32_fp8_fp8((long)(A), (long)(B), (C), 0, 0, 0)

// ---------------------------------------------------------------------------
// Kernel A: per pair-row i: norms + cross dot (fp32); write fp8 e4m3
// normalized rows Z[i], Z[i+NPAIR]; pos[i] = cos/T; zero rowsum (2/block).
// ---------------------------------------------------------------------------
__global__ __launch_bounds__(256) void normalize_kernel(
    const float* __restrict__ l1, const float* __restrict__ l2,
    unsigned char* __restrict__ Z, float* __restrict__ pos,
    float* __restrict__ rowsum) {
  const int i = blockIdx.x;
  const int t = threadIdx.x;           // one float4 per thread
  if (t < 2) rowsum[i * 2 + t] = 0.f;
  const float4 a = ((const float4*)(l1 + (size_t)i * DIM))[t];
  const float4 b = ((const float4*)(l2 + (size_t)i * DIM))[t];
  float s1 = a.x*a.x + a.y*a.y + a.z*a.z + a.w*a.w;
  float s2 = b.x*b.x + b.y*b.y + b.z*b.z + b.w*b.w;
  float d  = a.x*b.x + a.y*b.y + a.z*b.z + a.w*b.w;

  #pragma unroll
  for (int off = 32; off; off >>= 1) {
    s1 += __shfl_down(s1, off);
    s2 += __shfl_down(s2, off);
    d  += __shfl_down(d,  off);
  }
  __shared__ float red[3][4];
  __shared__ float fin[3];
  const int wave = t >> 6, lane = t & 63;
  if (lane == 0) { red[0][wave] = s1; red[1][wave] = s2; red[2][wave] = d; }
  __syncthreads();
  if (t == 0) {
    float S1 = red[0][0] + red[0][1] + red[0][2] + red[0][3];
    float S2 = red[1][0] + red[1][1] + red[1][2] + red[1][3];
    float DD = red[2][0] + red[2][1] + red[2][2] + red[2][3];
    float r1 = rsqrtf(S1), r2 = rsqrtf(S2);
    fin[0] = r1; fin[1] = r2;
    pos[i] = DD * r1 * r2 * INV_T;
  }
  __syncthreads();
  const float r1 = fin[0], r2 = fin[1];
  int pa = __builtin_amdgcn_cvt_pk_fp8_f32(a.x * r1, a.y * r1, 0, false);
  pa     = __builtin_amdgcn_cvt_pk_fp8_f32(a.z * r1, a.w * r1, pa, true);
  int pb = __builtin_amdgcn_cvt_pk_fp8_f32(b.x * r2, b.y * r2, 0, false);
  pb     = __builtin_amdgcn_cvt_pk_fp8_f32(b.z * r2, b.w * r2, pb, true);
  ((int*)(Z + (size_t)i * DIM))[t] = pa;
  ((int*)(Z + (size_t)(i + NPAIR) * DIM))[t] = pb;
}

// ---------------------------------------------------------------------------
// Kernel B1: 496 strict off-diagonal 256x256 cells (bi < bj), fp8.
// 3-buffer LDS (A[256][64]@0 + B[256][64]@16384 = 32 KB/buf, 96 KB),
// 2-deep prefetch via global_load_lds, counted vmcnt(4), 1 barrier/K-tile.
// 8 waves (2Mx4N), per wave 128x64 out: a[8][2], b[4][2] b64 frags,
// 64 MFMA 16x16x32 fp8 per K-tile; acc[8][4] in AGPRs.
// Swizzle: chunk_phys = chunk ^ ((r>>1)&3) on both stage-source and read.
// ---------------------------------------------------------------------------
__global__ __launch_bounds__(512, 2) void ntxent_gemm_offdiag(
    const unsigned char* __restrict__ Z, float* __restrict__ rowsum) {
  __shared__ unsigned char lds[3 * 32768];

  const int t    = threadIdx.x;
  const int wid  = t >> 6;
  const int lane = t & 63;
  const int lrow = lane & 15;
  const int kgrp = lane >> 4;
  const int wm   = wid >> 2;        // 0..1  (128-row half)
  const int wn   = wid & 3;         // 0..3  (64-col quarter)

  // T1: bijective XCD swizzle (496 = 8*62) + strict-upper decode (bi < bj).
  const int idx = (blockIdx.x & 7) * 62 + (blockIdx.x >> 3);
  int bj = (int)((1.0f + sqrtf(1.0f + 8.0f * (float)idx)) * 0.5f);
  while (bj * (bj - 1) / 2 > idx) --bj;
  while ((bj + 1) * bj / 2 <= idx) ++bj;
  const int bi = idx - bj * (bj - 1) / 2;
  const int brow = bi * 256, bcol = bj * 256;

  // Stage one 256x64 fp8 op-tile (16 KB = 1024 chunks -> 2 gloads/thread):
  // linear LDS dest, inverse chunk-swizzled global source.
  auto stage = [&](int kt, int buf, int rowbase, int opoff) {
    #pragma unroll
    for (int i = 0; i < 2; ++i) {
      const int cb = wid * 128 + i * 64;   // wave-uniform chunk base
      const int c  = cb + lane;
      const int r  = c >> 2;
      const int lc = (c & 3) ^ ((r >> 1) & 3);
      GLOAD_LDS16(Z + (size_t)(rowbase + r) * DIM + kt * 64 + lc * 16,
                  lds + buf * 32768 + opoff + cb * 16);
    }
  };
  // Read 8 fp8 at (row, k = kk*32 + kgrp*8) with the chunk swizzle.
  auto ld8 = [&](int buf, int opoff, int row, int kk) -> long {
    const int cl = kk * 2 + (kgrp >> 1);
    return *(const long*)(lds + buf * 32768 + opoff + row * 64
                          + ((cl ^ ((row >> 1) & 3)) << 4) + (kgrp & 1) * 8);
  };

  f32x4 acc[8][4];
  #pragma unroll
  for (int i = 0; i < 8; ++i)
    #pragma unroll
    for (int j = 0; j < 4; ++j) acc[i][j] = (f32x4){0.f, 0.f, 0.f, 0.f};

  // Prologue: stage tiles 0,1 (4 gloads each); drain tile 0 -> vmcnt(4).
  stage(0, 0, brow, 0); stage(0, 0, bcol, 16384);
  stage(1, 1, brow, 0); stage(1, 1, bcol, 16384);
  asm volatile("s_waitcnt vmcnt(4)" ::: "memory");
  __builtin_amdgcn_s_barrier();

  int bcur = 0, bnext = 1, bfree = 2;
  for (int kt = 0; kt < NKT; ++kt) {
    long a[8][2], b[4][2];
    #pragma unroll
    for (int mi = 0; mi < 8; ++mi)
      #pragma unroll
      for (int kk = 0; kk < 2; ++kk)
        a[mi][kk] = ld8(bcur, 0, wm * 128 + mi * 16 + lrow, kk);
    #pragma unroll
    for (int ni = 0; ni < 4; ++ni)
      #pragma unroll
      for (int kk = 0; kk < 2; ++kk)
        b[ni][kk] = ld8(bcur, 16384, wn * 64 + ni * 16 + lrow, kk);
    if (kt + 2 < NKT) {                  // prefetch 2 ahead (4 gloads)
      stage(kt + 2, bfree, brow, 0);
      stage(kt + 2, bfree, bcol, 16384);
    }
    asm volatile("s_waitcnt lgkmcnt(0)" ::: "memory");
    __builtin_amdgcn_sched_barrier(0);
    __builtin_amdgcn_s_setprio(1);
    #pragma unroll
    for (int kk = 0; kk < 2; ++kk)
      #pragma unroll
      for (int mi = 0; mi < 8; ++mi)
        #pragma unroll
        for (int ni = 0; ni < 4; ++ni)
          acc[mi][ni] = MFMA_FP8(a[mi][kk], b[ni][kk], acc[mi][ni]);
    __builtin_amdgcn_s_setprio(0);
    if (kt + 2 < NKT) {
      asm volatile("s_waitcnt vmcnt(4)" ::: "memory");   // tile kt+1 ready
    } else if (kt + 1 < NKT) {
      asm volatile("s_waitcnt vmcnt(0)" ::: "memory");   // last tile
    }
    __builtin_amdgcn_s_barrier();
    const int tmp = bcur; bcur = bnext; bnext = bfree; bfree = tmp;
  }

  // Epilogue. C/D layout (m89, dtype-independent): col = lane&15,
  // row = (lane>>4)*4 + j. Strict off-diag cell: no mask.
  #pragma unroll
  for (int mi = 0; mi < 8; ++mi)
    #pragma unroll
    for (int ni = 0; ni < 4; ++ni)
      #pragma unroll
      for (int j = 0; j < 4; ++j)
        acc[mi][ni][j] = __expf((acc[mi][ni][j] - 1.0f) * INV_T);
  // Row sums.
  #pragma unroll
  for (int mi = 0; mi < 8; ++mi) {
    float rs[4] = {0.f, 0.f, 0.f, 0.f};
    #pragma unroll
    for (int ni = 0; ni < 4; ++ni)
      #pragma unroll
      for (int j = 0; j < 4; ++j) rs[j] += acc[mi][ni][j];
    #pragma unroll
    for (int j = 0; j < 4; ++j) {
      float s = rs[j];
      s += __shfl_xor(s, 1);
      s += __shfl_xor(s, 2);
      s += __shfl_xor(s, 4);
      s += __shfl_xor(s, 8);
      if (lrow == 0)
        atomicAdd(&rowsum[brow + wm * 128 + mi * 16 + kgrp * 4 + j], s);
    }
  }
  // Col sums.
  #pragma unroll
  for (int ni = 0; ni < 4; ++ni) {
    float cs = 0.f;
    #pragma unroll
    for (int mi = 0; mi < 8; ++mi)
      cs += acc[mi][ni][0] + acc[mi][ni][1] + acc[mi][ni][2] + acc[mi][ni][3];
    cs += __shfl_xor(cs, 16);
    cs += __shfl_xor(cs, 32);
    if (kgrp == 0)
      atomicAdd(&rowsum[bcol + wn * 64 + ni * 16 + lrow], cs);
  }
}

// ---------------------------------------------------------------------------
// Kernel B2: diagonal band, fp8. 64 cells of 128x256; gcol > grow keeps each
// within-cell strict pair once. BK=64, 3 bufs x (A 8KB + B 16KB) = 72 KB,
// 2-deep prefetch, counted vmcnt(3), 1 barrier per K-tile. (R10 verbatim.)
// ---------------------------------------------------------------------------
__global__ __launch_bounds__(512, 2) void ntxent_gemm_diag(
    const unsigned char* __restrict__ Z, float* __restrict__ rowsum) {
  __shared__ unsigned char lds[3 * 24576];  // buf: A[128][64]@0, B[256][64]@8192

  const int t    = threadIdx.x;
  const int wid  = t >> 6;
  const int lane = t & 63;
  const int lrow = lane & 15;
  const int kgrp = lane >> 4;
  const int wm   = wid >> 2;        // 0..1: 64-row half of 128 rows
  const int wn   = wid & 3;         // 0..3: 64-col quarter of 256 cols

  const int d = blockIdx.x >> 1;
  const int arow0 = d * 256 + (blockIdx.x & 1) * 128;
  const int bcol0 = d * 256;

  auto stageA = [&](int kt, int buf) {       // 512 chunks -> 1 gload
    const int cb = wid * 64;
    const int c  = cb + lane;
    const int r  = c >> 2;
    const int lc = (c & 3) ^ ((r >> 1) & 3);
    GLOAD_LDS16(Z + (size_t)(arow0 + r) * DIM + kt * 64 + lc * 16,
                lds + buf * 24576 + cb * 16);
  };
  auto stageB = [&](int kt, int buf, int half) {   // 512 chunks each half
    const int cb = half * 512 + wid * 64;
    const int c  = cb + lane;
    const int r  = c >> 2;
    const int lc = (c & 3) ^ ((r >> 1) & 3);
    GLOAD_LDS16(Z + (size_t)(bcol0 + r) * DIM + kt * 64 + lc * 16,
                lds + buf * 24576 + 8192 + cb * 16);
  };
  auto ld8 = [&](int buf, int opoff, int row, int kk) -> long {
    const int cl = kk * 2 + (kgrp >> 1);
    return *(const long*)(lds + buf * 24576 + opoff + row * 64
                          + ((cl ^ ((row >> 1) & 3)) << 4) + (kgrp & 1) * 8);
  };

  f32x4 acc[4][4];
  #pragma unroll
  for (int i = 0; i < 4; ++i)
    #pragma unroll
    for (int j = 0; j < 4; ++j) acc[i][j] = (f32x4){0.f, 0.f, 0.f, 0.f};

  stageA(0, 0); stageB(0, 0, 0); stageB(0, 0, 1);
  stageA(1, 1); stageB(1, 1, 0); stageB(1, 1, 1);
  asm volatile("s_waitcnt vmcnt(3)" ::: "memory");
  __builtin_amdgcn_s_barrier();

  int bcur = 0, bnext = 1, bfree = 2;
  for (int kt = 0; kt < NKT; ++kt) {
    long a[4][2], b[4][2];
    #pragma unroll
    for (int mi = 0; mi < 4; ++mi)
      #pragma unroll
      for (int kk = 0; kk < 2; ++kk)
        a[mi][kk] = ld8(bcur, 0, wm * 64 + mi * 16 + lrow, kk);
    #pragma unroll
    for (int ni = 0; ni < 4; ++ni)
      #pragma unroll
      for (int kk = 0; kk < 2; ++kk)
        b[ni][kk] = ld8(bcur, 8192, wn * 64 + ni * 16 + lrow, kk);
    if (kt + 2 < NKT) {
      stageA(kt + 2, bfree);
      stageB(kt + 2, bfree, 0);
      stageB(kt + 2, bfree, 1);
    }
    asm volatile("s_waitcnt lgkmcnt(0)" ::: "memory");
    __builtin_amdgcn_sched_barrier(0);
    __builtin_amdgcn_s_setprio(1);
    #pragma unroll
    for (int kk = 0; kk < 2; ++kk)
      #pragma unroll
      for (int mi = 0; mi < 4; ++mi)
        #pragma unroll
        for (int ni = 0; ni < 4; ++ni)
          acc[mi][ni] = MFMA_FP8(a[mi][kk], b[ni][kk], acc[mi][ni]);
    __builtin_amdgcn_s_setprio(0);
    if (kt + 2 < NKT) {
      asm volatile("s_waitcnt vmcnt(3)" ::: "memory");
    } else if (kt + 1 < NKT) {
      asm volatile("s_waitcnt vmcnt(0)" ::: "memory");
    }
    __builtin_amdgcn_s_barrier();
    const int tmp = bcur; bcur = bnext; bnext = bfree; bfree = tmp;
  }

  // Keep only gcol > grow (each within-cell strict pair exactly once).
  #pragma unroll
  for (int mi = 0; mi < 4; ++mi)
    #pragma unroll
    for (int ni = 0; ni < 4; ++ni) {
      const int gcol = bcol0 + wn * 64 + ni * 16 + lrow;
      #pragma unroll
      for (int j = 0; j < 4; ++j) {
        const int grow = arow0 + wm * 64 + mi * 16 + kgrp * 4 + j;
        const float v = acc[mi][ni][j];
        acc[mi][ni][j] = (gcol > grow) ? __expf((v - 1.0f) * INV_T) : 0.f;
      }
    }
  #pragma unroll
  for (int mi = 0; mi < 4; ++mi) {
    float rs[4] = {0.f, 0.f, 0.f, 0.f};
    #pragma unroll
    for (int ni = 0; ni < 4; ++ni)
      #pragma unroll
      for (int j = 0; j < 4; ++j) rs[j] += acc[mi][ni][j];
    #pragma unroll
    for (int j = 0; j < 4; ++j) {
      float s = rs[j];
      s += __shfl_xor(s, 1);
      s += __shfl_xor(s, 2);
      s += __shfl_xor(s, 4);
      s += __shfl_xor(s, 8);
      if (lrow == 0)
        atomicAdd(&rowsum[arow0 + wm * 64 + mi * 16 + kgrp * 4 + j], s);
    }
  }
  #pragma unroll
  for (int ni = 0; ni < 4; ++ni) {
    float cs = 0.f;
    #pragma unroll
    for (int mi = 0; mi < 4; ++mi)
      cs += acc[mi][ni][0] + acc[mi][ni][1] + acc[mi][ni][2] + acc[mi][ni][3];
    cs += __shfl_xor(cs, 16);
    cs += __shfl_xor(cs, 32);
    if (kgrp == 0)
      atomicAdd(&rowsum[bcol0 + wn * 64 + ni * 16 + lrow], cs);
  }
}

// ---------------------------------------------------------------------------
// Kernel C: loss = 1/T + mean(log rowsum) - mean(pos)
// ---------------------------------------------------------------------------
__global__ __launch_bounds__(1024) void finalize_kernel(
    const float* __restrict__ rowsum, const float* __restrict__ pos,
    float* __restrict__ out) {
  const int t = threadIdx.x;
  float ls = 0.f, ps = 0.f;
  for (int i = t; i < NROWS; i += 1024) ls += logf(rowsum[i]);
  for (int i = t; i < NPAIR; i += 1024) ps += pos[i];
  #pragma unroll
  for (int off = 32; off; off >>= 1) {
    ls += __shfl_down(ls, off);
    ps += __shfl_down(ps, off);
  }
  __shared__ float sls[16], sps[16];
  const int wave = t >> 6, lane = t & 63;
  if (lane == 0) { sls[wave] = ls; sps[wave] = ps; }
  __syncthreads();
  if (t == 0) {
    float LS = 0.f, PS = 0.f;
    #pragma unroll
    for (int w = 0; w < 16; ++w) { LS += sls[w]; PS += sps[w]; }
    out[0] = INV_T + LS / (float)NROWS - PS / (float)NPAIR;
  }
}

extern "C" void kernel_launch(void* const* d_in, const int* in_sizes, int n_in,
                              void* d_out, int out_size, void* d_ws, size_t ws_size,
                              hipStream_t stream) {
  const float* l1 = (const float*)d_in[0];
  const float* l2 = (const float*)d_in[1];
  float* out = (float*)d_out;

  char* ws = (char*)d_ws;
  unsigned char* Z = (unsigned char*)ws;                   // 8 MB fp8
  float* rowsum = (float*)(ws + (size_t)NROWS * DIM);      // 32 KB
  float* pos    = rowsum + NROWS;                          // 16 KB

  normalize_kernel<<<NPAIR, 256, 0, stream>>>(l1, l2, Z, pos, rowsum);
  ntxent_gemm_offdiag<<<NOFF, 512, 0, stream>>>(Z, rowsum);
  ntxent_gemm_diag<<<64, 512, 0, stream>>>(Z, rowsum);
  finalize_kernel<<<1, 1024, 0, stream>>>(rowsum, pos, out);
}

// Round 12
// 91.894 us; speedup vs baseline: 4.2686x; 1.1185x over previous
//
#include <hip/hip_runtime.h>
#include <hip/hip_bf16.h>

// NT-Xent loss. N=4096 pairs, D=1024, 2N=8192 rows.
// loss = 1/T + mean_i log( sum_{j != i} exp(sim_ij - 1/T) ) - mean_i pos_i
// sim = Z Z^T (cosine); fixed max 1/T (cosine bound) -> no online max.
// R10: fp8 + fixed swizzle = 103 us. R11: 1-barrier/K-tile = null.
// Key R5/R10/R11 invariance: time flat under halved FLOPs, halved bytes,
// 8x fewer barriers -> bottleneck is the serial {reads -> lgkm(0) -> MFMA}
// per-wave phase structure (LDS phase never overlaps MFMA phase).
// R12: register-pipelined frags. Z stored k-PAIRED (chunk g = 8B of k-half0
// ++ 8B of k-half1) so one ds_read_b128 = both kk frags -> 12 reads/K-tile
// (<=15, counted lgkm encodable). Ping/pong P/Q frag sets: issue reads(kt+1)
// BEFORE MFMA(kt); compiler emits lgkmcnt(12) -> reads hide under MFMA.

#define NPAIR 4096
#define NROWS 8192
#define DIM   1024
#define NOFF  496                   // strict off-diag 256^2 cells (32*31/2)
#define NKT   16                    // K-tiles of 64
#define INV_T 14.285714285714286f   // 1/0.07

typedef __attribute__((ext_vector_type(4))) float f32x4;
typedef __attribute__((ext_vector_type(2))) long  i64x2;

#define GLOAD_LDS16(g, l)                                              \
  __builtin_amdgcn_global_load_lds(                                    \
      (const __attribute__((address_space(1))) void*)(g),              \
      (__attribute__((address_space(3))) void*)(l), 16, 0, 0)

#define MFMA_FP8(A, B, C)                                              \
  __builtin_amdgcn_mfma_f32_16x16x32_fp8_fp8((long)(A), (long)(B), (C), 0, 0, 0)

#define WAIT_VM0() asm volatile("s_waitcnt vmcnt(0)" ::: "memory")
#define BARRIER()  { __builtin_amdgcn_s_barrier();                     \
                     __builtin_amdgcn_sched_barrier(0); }

// ---------------------------------------------------------------------------
// Kernel A: per pair-row i: norms + cross dot (fp32); write fp8 e4m3
// normalized rows in k-PAIRED layout; pos[i] = cos/T; zero rowsum.
// k-paired: within each 64-elem K-tile, 16B chunk g holds k[g*8..g*8+8)
// of k-half 0 followed by k[32+g*8..+8) of k-half 1.
// Thread t covers k0 = 4t..4t+3 (same chunk, same half -> one int store).
// ---------------------------------------------------------------------------
__global__ __launch_bounds__(256) void normalize_kernel(
    const float* __restrict__ l1, const float* __restrict__ l2,
    unsigned char* __restrict__ Z, float* __restrict__ pos,
    float* __restrict__ rowsum) {
  const int i = blockIdx.x;
  const int t = threadIdx.x;           // one float4 per thread
  if (t < 2) rowsum[i * 2 + t] = 0.f;
  const float4 a = ((const float4*)(l1 + (size_t)i * DIM))[t];
  const float4 b = ((const float4*)(l2 + (size_t)i * DIM))[t];
  float s1 = a.x*a.x + a.y*a.y + a.z*a.z + a.w*a.w;
  float s2 = b.x*b.x + b.y*b.y + b.z*b.z + b.w*b.w;
  float d  = a.x*b.x + a.y*b.y + a.z*b.z + a.w*b.w;

  #pragma unroll
  for (int off = 32; off; off >>= 1) {
    s1 += __shfl_down(s1, off);
    s2 += __shfl_down(s2, off);
    d  += __shfl_down(d,  off);
  }
  __shared__ float red[3][4];
  __shared__ float fin[3];
  const int wave = t >> 6, lane = t & 63;
  if (lane == 0) { red[0][wave] = s1; red[1][wave] = s2; red[2][wave] = d; }
  __syncthreads();
  if (t == 0) {
    float S1 = red[0][0] + red[0][1] + red[0][2] + red[0][3];
    float S2 = red[1][0] + red[1][1] + red[1][2] + red[1][3];
    float DD = red[2][0] + red[2][1] + red[2][2] + red[2][3];
    float r1 = rsqrtf(S1), r2 = rsqrtf(S2);
    fin[0] = r1; fin[1] = r2;
    pos[i] = DD * r1 * r2 * INV_T;
  }
  __syncthreads();
  const float r1 = fin[0], r2 = fin[1];
  int pa = __builtin_amdgcn_cvt_pk_fp8_f32(a.x * r1, a.y * r1, 0, false);
  pa     = __builtin_amdgcn_cvt_pk_fp8_f32(a.z * r1, a.w * r1, pa, true);
  int pb = __builtin_amdgcn_cvt_pk_fp8_f32(b.x * r2, b.y * r2, 0, false);
  pb     = __builtin_amdgcn_cvt_pk_fp8_f32(b.z * r2, b.w * r2, pb, true);
  const int k0 = t * 4;
  const int noff = (k0 >> 6) * 64 + (((k0 >> 3) & 3) << 4)
                 + (((k0 >> 5) & 1) << 3) + (k0 & 7);
  *(int*)(Z + (size_t)i * DIM + noff) = pa;
  *(int*)(Z + (size_t)(i + NPAIR) * DIM + noff) = pb;
}

// ---------------------------------------------------------------------------
// Kernel B1: 496 strict off-diagonal 256x256 cells (bi < bj), fp8,
// register-pipelined. 3-buffer LDS (A[256][64]@0 + B[256][64]@16384 =
// 32 KB/buf). Per half-iter j: {vmcnt(0); barrier; read frags(j+1) [12
// ds_read_b128] into alt reg set; stage(j+2) [4 gloads]; MFMA(j) from
// current set}. Compiler emits counted lgkmcnt -> reads overlap MFMA.
// Swizzle: phys chunk = logical ^ ((r>>1)&3), both sides; for frag reads
// the row-dependent part is lane-constant ((mi*16)>>1 == 0 mod 4).
// ---------------------------------------------------------------------------
__global__ __launch_bounds__(512, 2) void ntxent_gemm_offdiag(
    const unsigned char* __restrict__ Z, float* __restrict__ rowsum) {
  __shared__ unsigned char lds[3 * 32768];

  const int t    = threadIdx.x;
  const int wid  = t >> 6;
  const int lane = t & 63;
  const int lrow = lane & 15;
  const int kgrp = lane >> 4;
  const int wm   = wid >> 2;        // 0..1  (128-row half)
  const int wn   = wid & 3;         // 0..3  (64-col quarter)

  // T1: bijective XCD swizzle (496 = 8*62) + strict-upper decode (bi < bj).
  const int idx = (blockIdx.x & 7) * 62 + (blockIdx.x >> 3);
  int bj = (int)((1.0f + sqrtf(1.0f + 8.0f * (float)idx)) * 0.5f);
  while (bj * (bj - 1) / 2 > idx) --bj;
  while ((bj + 1) * bj / 2 <= idx) ++bj;
  const int bi = idx - bj * (bj - 1) / 2;
  const int brow = bi * 256, bcol = bj * 256;

  // Stage one K-tile (A 256x64 + B 256x64 = 4 gloads/thread).
  auto stage_tile = [&](int kt, int bufoff) {
    #pragma unroll
    for (int op = 0; op < 2; ++op) {
      const int rowbase = op ? bcol : brow;
      const int opoff   = op ? 16384 : 0;
      #pragma unroll
      for (int i = 0; i < 2; ++i) {
        const int cb = wid * 128 + i * 64;   // wave-uniform chunk base
        const int c  = cb + lane;
        const int r  = c >> 2;
        const int lc = (c & 3) ^ ((r >> 1) & 3);
        GLOAD_LDS16(Z + (size_t)(rowbase + r) * DIM + kt * 64 + lc * 16,
                    lds + bufoff + opoff + cb * 16);
      }
    }
  };
  // One b128 read = both kk fragments of (row, kgrp) in k-paired layout.
  auto ld16 = [&](int bufoff, int opoff, int row) -> i64x2 {
    return *(const i64x2*)(lds + bufoff + opoff + row * 64
                           + ((kgrp ^ ((row >> 1) & 3)) << 4));
  };

  i64x2 pa[8], pb[4], qa[8], qb[4];
  f32x4 acc[8][4];
  #pragma unroll
  for (int i = 0; i < 8; ++i)
    #pragma unroll
    for (int j = 0; j < 4; ++j) acc[i][j] = (f32x4){0.f, 0.f, 0.f, 0.f};

#define READF(A_, B_, BO)                                              \
  { _Pragma("unroll") for (int mi = 0; mi < 8; ++mi)                   \
      A_[mi] = ld16((BO), 0, wm * 128 + mi * 16 + lrow);               \
    _Pragma("unroll") for (int ni = 0; ni < 4; ++ni)                   \
      B_[ni] = ld16((BO), 16384, wn * 64 + ni * 16 + lrow); }
#define MMF(A_, B_)                                                    \
  { __builtin_amdgcn_s_setprio(1);                                     \
    _Pragma("unroll") for (int mi = 0; mi < 8; ++mi)                   \
    _Pragma("unroll") for (int ni = 0; ni < 4; ++ni)                   \
      acc[mi][ni] = MFMA_FP8(A_[mi].x, B_[ni].x, acc[mi][ni]);         \
    _Pragma("unroll") for (int mi = 0; mi < 8; ++mi)                   \
    _Pragma("unroll") for (int ni = 0; ni < 4; ++ni)                   \
      acc[mi][ni] = MFMA_FP8(A_[mi].y, B_[ni].y, acc[mi][ni]);         \
    __builtin_amdgcn_s_setprio(0); }

  int oA = 0, oB = 32768, oC = 65536;   // rotating buffer byte offsets
  // Prologue: stage tiles 0,1; drain; read frags(0).
  stage_tile(0, oA);
  stage_tile(1, oB);
  WAIT_VM0();
  __syncthreads();
  READF(pa, pb, oA);

  for (int I = 0; I < 8; ++I) {
    const int j = 2 * I;
    // ---- even half: MFMA(j) from P, read frags(j+1) into Q ----
    WAIT_VM0();                       // stage(j+1)/(j) landed
    BARRIER();
    READF(qa, qb, oB);                // frags(j+1)
    if (j + 2 < NKT) stage_tile(j + 2, oC);
    MMF(pa, pb);                      // compiler waits only P's reads
    { const int tmp = oA; oA = oB; oB = oC; oC = tmp; }
    // ---- odd half: MFMA(j+1) from Q, read frags(j+2) into P ----
    WAIT_VM0();                       // stage(j+2) landed (covered by MM)
    BARRIER();
    if (j + 2 < NKT) READF(pa, pb, oB);
    if (j + 3 < NKT) stage_tile(j + 3, oC);
    MMF(qa, qb);
    { const int tmp = oA; oA = oB; oB = oC; oC = tmp; }
  }

  // Epilogue. C/D layout (m89, dtype-independent): col = lane&15,
  // row = (lane>>4)*4 + j. Strict off-diag cell: no mask.
  #pragma unroll
  for (int mi = 0; mi < 8; ++mi)
    #pragma unroll
    for (int ni = 0; ni < 4; ++ni)
      #pragma unroll
      for (int j = 0; j < 4; ++j)
        acc[mi][ni][j] = __expf((acc[mi][ni][j] - 1.0f) * INV_T);
  // Row sums.
  #pragma unroll
  for (int mi = 0; mi < 8; ++mi) {
    float rs[4] = {0.f, 0.f, 0.f, 0.f};
    #pragma unroll
    for (int ni = 0; ni < 4; ++ni)
      #pragma unroll
      for (int j = 0; j < 4; ++j) rs[j] += acc[mi][ni][j];
    #pragma unroll
    for (int j = 0; j < 4; ++j) {
      float s = rs[j];
      s += __shfl_xor(s, 1);
      s += __shfl_xor(s, 2);
      s += __shfl_xor(s, 4);
      s += __shfl_xor(s, 8);
      if (lrow == 0)
        atomicAdd(&rowsum[brow + wm * 128 + mi * 16 + kgrp * 4 + j], s);
    }
  }
  // Col sums.
  #pragma unroll
  for (int ni = 0; ni < 4; ++ni) {
    float cs = 0.f;
    #pragma unroll
    for (int mi = 0; mi < 8; ++mi)
      cs += acc[mi][ni][0] + acc[mi][ni][1] + acc[mi][ni][2] + acc[mi][ni][3];
    cs += __shfl_xor(cs, 16);
    cs += __shfl_xor(cs, 32);
    if (kgrp == 0)
      atomicAdd(&rowsum[bcol + wn * 64 + ni * 16 + lrow], cs);
  }
#undef READF
#undef MMF
}

// ---------------------------------------------------------------------------
// Kernel B2: diagonal band, fp8, k-paired layout. 64 cells of 128x256;
// gcol > grow keeps each within-cell strict pair once. BK=64, 3 bufs x
// (A 8KB + B 16KB) = 72 KB, 2-deep prefetch, counted vmcnt(3),
// 1 barrier per K-tile. b128 frag reads (.x = kk0, .y = kk1).
// ---------------------------------------------------------------------------
__global__ __launch_bounds__(512, 2) void ntxent_gemm_diag(
    const unsigned char* __restrict__ Z, float* __restrict__ rowsum) {
  __shared__ unsigned char lds[3 * 24576];  // buf: A[128][64]@0, B[256][64]@8192

  const int t    = threadIdx.x;
  const int wid  = t >> 6;
  const int lane = t & 63;
  const int lrow = lane & 15;
  const int kgrp = lane >> 4;
  const int wm   = wid >> 2;        // 0..1: 64-row half of 128 rows
  const int wn   = wid & 3;         // 0..3: 64-col quarter of 256 cols

  const int d = blockIdx.x >> 1;
  const int arow0 = d * 256 + (blockIdx.x & 1) * 128;
  const int bcol0 = d * 256;

  auto stageA = [&](int kt, int buf) {       // 512 chunks -> 1 gload
    const int cb = wid * 64;
    const int c  = cb + lane;
    const int r  = c >> 2;
    const int lc = (c & 3) ^ ((r >> 1) & 3);
    GLOAD_LDS16(Z + (size_t)(arow0 + r) * DIM + kt * 64 + lc * 16,
                lds + buf * 24576 + cb * 16);
  };
  auto stageB = [&](int kt, int buf, int half) {   // 512 chunks each half
    const int cb = half * 512 + wid * 64;
    const int c  = cb + lane;
    const int r  = c >> 2;
    const int lc = (c & 3) ^ ((r >> 1) & 3);
    GLOAD_LDS16(Z + (size_t)(bcol0 + r) * DIM + kt * 64 + lc * 16,
                lds + buf * 24576 + 8192 + cb * 16);
  };
  auto ld16 = [&](int buf, int opoff, int row) -> i64x2 {
    return *(const i64x2*)(lds + buf * 24576 + opoff + row * 64
                           + ((kgrp ^ ((row >> 1) & 3)) << 4));
  };

  f32x4 acc[4][4];
  #pragma unroll
  for (int i = 0; i < 4; ++i)
    #pragma unroll
    for (int j = 0; j < 4; ++j) acc[i][j] = (f32x4){0.f, 0.f, 0.f, 0.f};

  stageA(0, 0); stageB(0, 0, 0); stageB(0, 0, 1);
  stageA(1, 1); stageB(1, 1, 0); stageB(1, 1, 1);
  asm volatile("s_waitcnt vmcnt(3)" ::: "memory");
  __builtin_amdgcn_s_barrier();

  int bcur = 0, bnext = 1, bfree = 2;
  for (int kt = 0; kt < NKT; ++kt) {
    i64x2 a[4], b[4];
    #pragma unroll
    for (int mi = 0; mi < 4; ++mi)
      a[mi] = ld16(bcur, 0, wm * 64 + mi * 16 + lrow);
    #pragma unroll
    for (int ni = 0; ni < 4; ++ni)
      b[ni] = ld16(bcur, 8192, wn * 64 + ni * 16 + lrow);
    if (kt + 2 < NKT) {
      stageA(kt + 2, bfree);
      stageB(kt + 2, bfree, 0);
      stageB(kt + 2, bfree, 1);
    }
    asm volatile("s_waitcnt lgkmcnt(0)" ::: "memory");
    __builtin_amdgcn_sched_barrier(0);
    __builtin_amdgcn_s_setprio(1);
    #pragma unroll
    for (int mi = 0; mi < 4; ++mi)
      #pragma unroll
      for (int ni = 0; ni < 4; ++ni)
        acc[mi][ni] = MFMA_FP8(a[mi].x, b[ni].x, acc[mi][ni]);
    #pragma unroll
    for (int mi = 0; mi < 4; ++mi)
      #pragma unroll
      for (int ni = 0; ni < 4; ++ni)
        acc[mi][ni] = MFMA_FP8(a[mi].y, b[ni].y, acc[mi][ni]);
    __builtin_amdgcn_s_setprio(0);
    if (kt + 2 < NKT) {
      asm volatile("s_waitcnt vmcnt(3)" ::: "memory");
    } else if (kt + 1 < NKT) {
      asm volatile("s_waitcnt vmcnt(0)" ::: "memory");
    }
    __builtin_amdgcn_s_barrier();
    const int tmp = bcur; bcur = bnext; bnext = bfree; bfree = tmp;
  }

  // Keep only gcol > grow (each within-cell strict pair exactly once).
  #pragma unroll
  for (int mi = 0; mi < 4; ++mi)
    #pragma unroll
    for (int ni = 0; ni < 4; ++ni) {
      const int gcol = bcol0 + wn * 64 + ni * 16 + lrow;
      #pragma unroll
      for (int j = 0; j < 4; ++j) {
        const int grow = arow0 + wm * 64 + mi * 16 + kgrp * 4 + j;
        const float v = acc[mi][ni][j];
        acc[mi][ni][j] = (gcol > grow) ? __expf((v - 1.0f) * INV_T) : 0.f;
      }
    }
  #pragma unroll
  for (int mi = 0; mi < 4; ++mi) {
    float rs[4] = {0.f, 0.f, 0.f, 0.f};
    #pragma unroll
    for (int ni = 0; ni < 4; ++ni)
      #pragma unroll
      for (int j = 0; j < 4; ++j) rs[j] += acc[mi][ni][j];
    #pragma unroll
    for (int j = 0; j < 4; ++j) {
      float s = rs[j];
      s += __shfl_xor(s, 1);
      s += __shfl_xor(s, 2);
      s += __shfl_xor(s, 4);
      s += __shfl_xor(s, 8);
      if (lrow == 0)
        atomicAdd(&rowsum[arow0 + wm * 64 + mi * 16 + kgrp * 4 + j], s);
    }
  }
  #pragma unroll
  for (int ni = 0; ni < 4; ++ni) {
    float cs = 0.f;
    #pragma unroll
    for (int mi = 0; mi < 4; ++mi)
      cs += acc[mi][ni][0] + acc[mi][ni][1] + acc[mi][ni][2] + acc[mi][ni][3];
    cs += __shfl_xor(cs, 16);
    cs += __shfl_xor(cs, 32);
    if (kgrp == 0)
      atomicAdd(&rowsum[bcol0 + wn * 64 + ni * 16 + lrow], cs);
  }
}

// ---------------------------------------------------------------------------
// Kernel C: loss = 1/T + mean(log rowsum) - mean(pos)
// ---------------------------------------------------------------------------
__global__ __launch_bounds__(1024) void finalize_kernel(
    const float* __restrict__ rowsum, const float* __restrict__ pos,
    float* __restrict__ out) {
  const int t = threadIdx.x;
  float ls = 0.f, ps = 0.f;
  for (int i = t; i < NROWS; i += 1024) ls += logf(rowsum[i]);
  for (int i = t; i < NPAIR; i += 1024) ps += pos[i];
  #pragma unroll
  for (int off = 32; off; off >>= 1) {
    ls += __shfl_down(ls, off);
    ps += __shfl_down(ps, off);
  }
  __shared__ float sls[16], sps[16];
  const int wave = t >> 6, lane = t & 63;
  if (lane == 0) { sls[wave] = ls; sps[wave] = ps; }
  __syncthreads();
  if (t == 0) {
    float LS = 0.f, PS = 0.f;
    #pragma unroll
    for (int w = 0; w < 16; ++w) { LS += sls[w]; PS += sps[w]; }
    out[0] = INV_T + LS / (float)NROWS - PS / (float)NPAIR;
  }
}

extern "C" void kernel_launch(void* const* d_in, const int* in_sizes, int n_in,
                              void* d_out, int out_size, void* d_ws, size_t ws_size,
                              hipStream_t stream) {
  const float* l1 = (const float*)d_in[0];
  const float* l2 = (const float*)d_in[1];
  float* out = (float*)d_out;

  char* ws = (char*)d_ws;
  unsigned char* Z = (unsigned char*)ws;                   // 8 MB fp8 (k-paired)
  float* rowsum = (float*)(ws + (size_t)NROWS * DIM);      // 32 KB
  float* pos    = rowsum + NROWS;                          // 16 KB

  normalize_kernel<<<NPAIR, 256, 0, stream>>>(l1, l2, Z, pos, rowsum);
  ntxent_gemm_offdiag<<<NOFF, 512, 0, stream>>>(Z, rowsum);
  ntxent_gemm_diag<<<64, 512, 0, stream>>>(Z, rowsum);
  finalize_kernel<<<1, 1024, 0, stream>>>(rowsum, pos, out);
}

// Round 13
// 91.047 us; speedup vs baseline: 4.3084x; 1.0093x over previous
//
#include <hip/hip_runtime.h>
#include <hip/hip_bf16.h>

// NT-Xent loss. N=4096 pairs, D=1024, 2N=8192 rows.
// loss = 1/T + mean_i log( sum_{j != i} exp(sim_ij - 1/T) ) - mean_i pos_i
// sim = Z Z^T (cosine); fixed max 1/T (cosine bound) -> no online max.
// R10: fp8 + fixed swizzle. R12: register-pipelined frags (k-paired Z,
//      12 b128 reads/K-tile, ping-pong P/Q) -> 91.9 us, MfmaUtil 39.5.
// R13: (a) 4-buffer stage-3-ahead + counted vmcnt(4) (T4: never drain to 0
//      in steady state; loads get 2 MFMA phases of cover);
//      (b) diag band merged into the SAME dispatch as 96 tail blocks of
//      128x128 (skip the all-below-diagonal quarter) -> no serial dispatch.

#define NPAIR 4096
#define NROWS 8192
#define DIM   1024
#define NOFF  496                   // strict off-diag 256^2 cells (32*31/2)
#define NTAIL 96                    // diag band: 32 d-blocks x 3 subcells
#define NKT   16                    // K-tiles of 64
#define INV_T 14.285714285714286f   // 1/0.07

typedef __attribute__((ext_vector_type(4))) float f32x4;
typedef __attribute__((ext_vector_type(2))) long  i64x2;

#define GLOAD_LDS16(g, l)                                              \
  __builtin_amdgcn_global_load_lds(                                    \
      (const __attribute__((address_space(1))) void*)(g),              \
      (__attribute__((address_space(3))) void*)(l), 16, 0, 0)

#define MFMA_FP8(A, B, C)                                              \
  __builtin_amdgcn_mfma_f32_16x16x32_fp8_fp8((long)(A), (long)(B), (C), 0, 0, 0)

#define WAIT_VM(N)  asm volatile("s_waitcnt vmcnt(" #N ")" ::: "memory")
#define BARRIER()   { __builtin_amdgcn_s_barrier();                    \
                      __builtin_amdgcn_sched_barrier(0); }

// ---------------------------------------------------------------------------
// Kernel A: per pair-row i: norms + cross dot (fp32); write fp8 e4m3
// normalized rows in k-PAIRED layout (16B chunk g = 8B of k-half0 ++ 8B of
// k-half1 within each 64-k tile); pos[i] = cos/T; zero rowsum (2/block).
// ---------------------------------------------------------------------------
__global__ __launch_bounds__(256) void normalize_kernel(
    const float* __restrict__ l1, const float* __restrict__ l2,
    unsigned char* __restrict__ Z, float* __restrict__ pos,
    float* __restrict__ rowsum) {
  const int i = blockIdx.x;
  const int t = threadIdx.x;           // one float4 per thread
  if (t < 2) rowsum[i * 2 + t] = 0.f;
  const float4 a = ((const float4*)(l1 + (size_t)i * DIM))[t];
  const float4 b = ((const float4*)(l2 + (size_t)i * DIM))[t];
  float s1 = a.x*a.x + a.y*a.y + a.z*a.z + a.w*a.w;
  float s2 = b.x*b.x + b.y*b.y + b.z*b.z + b.w*b.w;
  float d  = a.x*b.x + a.y*b.y + a.z*b.z + a.w*b.w;

  #pragma unroll
  for (int off = 32; off; off >>= 1) {
    s1 += __shfl_down(s1, off);
    s2 += __shfl_down(s2, off);
    d  += __shfl_down(d,  off);
  }
  __shared__ float red[3][4];
  __shared__ float fin[3];
  const int wave = t >> 6, lane = t & 63;
  if (lane == 0) { red[0][wave] = s1; red[1][wave] = s2; red[2][wave] = d; }
  __syncthreads();
  if (t == 0) {
    float S1 = red[0][0] + red[0][1] + red[0][2] + red[0][3];
    float S2 = red[1][0] + red[1][1] + red[1][2] + red[1][3];
    float DD = red[2][0] + red[2][1] + red[2][2] + red[2][3];
    float r1 = rsqrtf(S1), r2 = rsqrtf(S2);
    fin[0] = r1; fin[1] = r2;
    pos[i] = DD * r1 * r2 * INV_T;
  }
  __syncthreads();
  const float r1 = fin[0], r2 = fin[1];
  int pa = __builtin_amdgcn_cvt_pk_fp8_f32(a.x * r1, a.y * r1, 0, false);
  pa     = __builtin_amdgcn_cvt_pk_fp8_f32(a.z * r1, a.w * r1, pa, true);
  int pb = __builtin_amdgcn_cvt_pk_fp8_f32(b.x * r2, b.y * r2, 0, false);
  pb     = __builtin_amdgcn_cvt_pk_fp8_f32(b.z * r2, b.w * r2, pb, true);
  const int k0 = t * 4;
  const int noff = (k0 >> 6) * 64 + (((k0 >> 3) & 3) << 4)
                 + (((k0 >> 5) & 1) << 3) + (k0 & 7);
  *(int*)(Z + (size_t)i * DIM + noff) = pa;
  *(int*)(Z + (size_t)(i + NPAIR) * DIM + noff) = pb;
}

// ---------------------------------------------------------------------------
// Kernel B: single dispatch, 592 blocks.
//  blocks [0,496): strict off-diagonal 256x256 cells (bi < bj), fp8,
//    register-pipelined, 4-buffer stage-3-ahead, counted vmcnt(4).
//  blocks [496,592): diag-band tail, 128x128 cells (3 per 256-row block:
//    upper-tri / full / lower-tri; gcol>grow mask), 3-buffer pipeline.
// ---------------------------------------------------------------------------
__global__ __launch_bounds__(512, 2) void ntxent_gemm_all(
    const unsigned char* __restrict__ Z, float* __restrict__ rowsum) {
  __shared__ unsigned char lds[131072];   // offdiag: 4 x 32 KB; tail: 3 x 16 KB

  const int t    = threadIdx.x;
  const int wid  = t >> 6;
  const int lane = t & 63;
  const int lrow = lane & 15;
  const int kgrp = lane >> 4;

  if (blockIdx.x < NOFF) {
    // =========================== off-diagonal path ==========================
    const int wm = wid >> 2;        // 0..1  (128-row half)
    const int wn = wid & 3;         // 0..3  (64-col quarter)

    // T1: bijective XCD swizzle (496 = 8*62) + strict-upper decode.
    const int idx = (blockIdx.x & 7) * 62 + (blockIdx.x >> 3);
    int bj = (int)((1.0f + sqrtf(1.0f + 8.0f * (float)idx)) * 0.5f);
    while (bj * (bj - 1) / 2 > idx) --bj;
    while ((bj + 1) * bj / 2 <= idx) ++bj;
    const int bi = idx - bj * (bj - 1) / 2;
    const int brow = bi * 256, bcol = bj * 256;

    // Stage one K-tile (A 256x64 + B 256x64 = 4 gloads/thread).
    auto stage_tile = [&](int kt, int bufoff) {
      #pragma unroll
      for (int op = 0; op < 2; ++op) {
        const int rowbase = op ? bcol : brow;
        const int opoff   = op ? 16384 : 0;
        #pragma unroll
        for (int i = 0; i < 2; ++i) {
          const int cb = wid * 128 + i * 64;   // wave-uniform chunk base
          const int c  = cb + lane;
          const int r  = c >> 2;
          const int lc = (c & 3) ^ ((r >> 1) & 3);
          GLOAD_LDS16(Z + (size_t)(rowbase + r) * DIM + kt * 64 + lc * 16,
                      lds + bufoff + opoff + cb * 16);
        }
      }
    };
    auto ld16 = [&](int bufoff, int opoff, int row) -> i64x2 {
      return *(const i64x2*)(lds + bufoff + opoff + row * 64
                             + ((kgrp ^ ((row >> 1) & 3)) << 4));
    };

    i64x2 pa[8], pb[4], qa[8], qb[4];
    f32x4 acc[8][4];
    #pragma unroll
    for (int i = 0; i < 8; ++i)
      #pragma unroll
      for (int j = 0; j < 4; ++j) acc[i][j] = (f32x4){0.f, 0.f, 0.f, 0.f};

#define READF(A_, B_, BO)                                              \
  { _Pragma("unroll") for (int mi = 0; mi < 8; ++mi)                   \
      A_[mi] = ld16((BO), 0, wm * 128 + mi * 16 + lrow);               \
    _Pragma("unroll") for (int ni = 0; ni < 4; ++ni)                   \
      B_[ni] = ld16((BO), 16384, wn * 64 + ni * 16 + lrow); }
#define MMF(A_, B_)                                                    \
  { __builtin_amdgcn_s_setprio(1);                                     \
    _Pragma("unroll") for (int mi = 0; mi < 8; ++mi)                   \
    _Pragma("unroll") for (int ni = 0; ni < 4; ++ni)                   \
      acc[mi][ni] = MFMA_FP8(A_[mi].x, B_[ni].x, acc[mi][ni]);         \
    _Pragma("unroll") for (int mi = 0; mi < 8; ++mi)                   \
    _Pragma("unroll") for (int ni = 0; ni < 4; ++ni)                   \
      acc[mi][ni] = MFMA_FP8(A_[mi].y, B_[ni].y, acc[mi][ni]);         \
    __builtin_amdgcn_s_setprio(0); }

    // Prologue: stage tiles 0,1,2; wait tile 0 (vmcnt 8); read frags(0).
    stage_tile(0, 0);
    stage_tile(1, 32768);
    stage_tile(2, 65536);
    WAIT_VM(8);
    __syncthreads();
    READF(pa, pb, 0);

    // Phase h: MMF(tile h), READF(tile h+1), stage(tile h+3).
    // vmcnt(4) guarantees stage(h+1) landed (only stage(h+2) may fly).
    #pragma unroll
    for (int h = 0; h < NKT; ++h) {
      const int bo_next  = ((h + 1) & 3) * 32768;
      const int bo_stage = ((h + 3) & 3) * 32768;
      if (h <= NKT - 3) { WAIT_VM(4); } else { WAIT_VM(0); }
      BARRIER();
      if (h + 1 < NKT) {
        if (h & 1) { READF(pa, pb, bo_next); }
        else       { READF(qa, qb, bo_next); }
      }
      if (h + 3 < NKT) stage_tile(h + 3, bo_stage);
      if (h & 1) { MMF(qa, qb); } else { MMF(pa, pb); }
    }
#undef READF
#undef MMF

    // Epilogue. C/D layout (m89): col = lane&15, row = (lane>>4)*4 + j.
    #pragma unroll
    for (int mi = 0; mi < 8; ++mi)
      #pragma unroll
      for (int ni = 0; ni < 4; ++ni)
        #pragma unroll
        for (int j = 0; j < 4; ++j)
          acc[mi][ni][j] = __expf((acc[mi][ni][j] - 1.0f) * INV_T);
    #pragma unroll
    for (int mi = 0; mi < 8; ++mi) {
      float rs[4] = {0.f, 0.f, 0.f, 0.f};
      #pragma unroll
      for (int ni = 0; ni < 4; ++ni)
        #pragma unroll
        for (int j = 0; j < 4; ++j) rs[j] += acc[mi][ni][j];
      #pragma unroll
      for (int j = 0; j < 4; ++j) {
        float s = rs[j];
        s += __shfl_xor(s, 1);
        s += __shfl_xor(s, 2);
        s += __shfl_xor(s, 4);
        s += __shfl_xor(s, 8);
        if (lrow == 0)
          atomicAdd(&rowsum[brow + wm * 128 + mi * 16 + kgrp * 4 + j], s);
      }
    }
    #pragma unroll
    for (int ni = 0; ni < 4; ++ni) {
      float cs = 0.f;
      #pragma unroll
      for (int mi = 0; mi < 8; ++mi)
        cs += acc[mi][ni][0] + acc[mi][ni][1] + acc[mi][ni][2] + acc[mi][ni][3];
      cs += __shfl_xor(cs, 16);
      cs += __shfl_xor(cs, 32);
      if (kgrp == 0)
        atomicAdd(&rowsum[bcol + wn * 64 + ni * 16 + lrow], cs);
    }
  } else {
    // ============================ diag-band tail ============================
    // 96 blocks of 128x128: b2 = 3d + ty; ty0 = upper-tri (r0,c0),
    // ty1 = full (r0,c1), ty2 = lower-tri of (r1,c1). gcol>grow masks all.
    const int b2 = blockIdx.x - NOFF;
    const int d  = b2 / 3, ty = b2 - d * 3;
    const int arow0 = d * 256 + (ty == 2 ? 128 : 0);
    const int bcol0 = d * 256 + (ty >= 1 ? 128 : 0);
    const int wm = wid >> 2;        // 0..1: 64-row half of 128 rows
    const int wn = wid & 3;         // 0..3: 32-col quarter of 128 cols

    auto stage = [&](int kt, int buf, int rowbase, int opoff) {
      const int cb = wid * 64;      // 512 chunks -> 1 gload/thread
      const int c  = cb + lane;
      const int r  = c >> 2;
      const int lc = (c & 3) ^ ((r >> 1) & 3);
      GLOAD_LDS16(Z + (size_t)(rowbase + r) * DIM + kt * 64 + lc * 16,
                  lds + buf * 16384 + opoff + cb * 16);
    };
    auto ld16 = [&](int buf, int opoff, int row) -> i64x2 {
      return *(const i64x2*)(lds + buf * 16384 + opoff + row * 64
                             + ((kgrp ^ ((row >> 1) & 3)) << 4));
    };

    f32x4 acc[4][2];
    #pragma unroll
    for (int i = 0; i < 4; ++i)
      #pragma unroll
      for (int j = 0; j < 2; ++j) acc[i][j] = (f32x4){0.f, 0.f, 0.f, 0.f};

    stage(0, 0, arow0, 0); stage(0, 0, bcol0, 8192);
    stage(1, 1, arow0, 0); stage(1, 1, bcol0, 8192);
    WAIT_VM(2);
    __builtin_amdgcn_s_barrier();

    int bcur = 0, bnext = 1, bfree = 2;
    for (int kt = 0; kt < NKT; ++kt) {
      i64x2 a[4], b[2];
      #pragma unroll
      for (int mi = 0; mi < 4; ++mi)
        a[mi] = ld16(bcur, 0, wm * 64 + mi * 16 + lrow);
      #pragma unroll
      for (int ni = 0; ni < 2; ++ni)
        b[ni] = ld16(bcur, 8192, wn * 32 + ni * 16 + lrow);
      if (kt + 2 < NKT) {
        stage(kt + 2, bfree, arow0, 0);
        stage(kt + 2, bfree, bcol0, 8192);
      }
      asm volatile("s_waitcnt lgkmcnt(0)" ::: "memory");
      __builtin_amdgcn_sched_barrier(0);
      __builtin_amdgcn_s_setprio(1);
      #pragma unroll
      for (int mi = 0; mi < 4; ++mi)
        #pragma unroll
        for (int ni = 0; ni < 2; ++ni)
          acc[mi][ni] = MFMA_FP8(a[mi].x, b[ni].x, acc[mi][ni]);
      #pragma unroll
      for (int mi = 0; mi < 4; ++mi)
        #pragma unroll
        for (int ni = 0; ni < 2; ++ni)
          acc[mi][ni] = MFMA_FP8(a[mi].y, b[ni].y, acc[mi][ni]);
      __builtin_amdgcn_s_setprio(0);
      if (kt + 2 < NKT) { WAIT_VM(2); }
      else if (kt + 1 < NKT) { WAIT_VM(0); }
      __builtin_amdgcn_s_barrier();
      const int tmp = bcur; bcur = bnext; bnext = bfree; bfree = tmp;
    }

    // Keep only gcol > grow (full cells satisfy it everywhere).
    #pragma unroll
    for (int mi = 0; mi < 4; ++mi)
      #pragma unroll
      for (int ni = 0; ni < 2; ++ni) {
        const int gcol = bcol0 + wn * 32 + ni * 16 + lrow;
        #pragma unroll
        for (int j = 0; j < 4; ++j) {
          const int grow = arow0 + wm * 64 + mi * 16 + kgrp * 4 + j;
          const float v = acc[mi][ni][j];
          acc[mi][ni][j] = (gcol > grow) ? __expf((v - 1.0f) * INV_T) : 0.f;
        }
      }
    #pragma unroll
    for (int mi = 0; mi < 4; ++mi) {
      float rs[4] = {0.f, 0.f, 0.f, 0.f};
      #pragma unroll
      for (int ni = 0; ni < 2; ++ni)
        #pragma unroll
        for (int j = 0; j < 4; ++j) rs[j] += acc[mi][ni][j];
      #pragma unroll
      for (int j = 0; j < 4; ++j) {
        float s = rs[j];
        s += __shfl_xor(s, 1);
        s += __shfl_xor(s, 2);
        s += __shfl_xor(s, 4);
        s += __shfl_xor(s, 8);
        if (lrow == 0)
          atomicAdd(&rowsum[arow0 + wm * 64 + mi * 16 + kgrp * 4 + j], s);
      }
    }
    #pragma unroll
    for (int ni = 0; ni < 2; ++ni) {
      float cs = 0.f;
      #pragma unroll
      for (int mi = 0; mi < 4; ++mi)
        cs += acc[mi][ni][0] + acc[mi][ni][1] + acc[mi][ni][2] + acc[mi][ni][3];
      cs += __shfl_xor(cs, 16);
      cs += __shfl_xor(cs, 32);
      if (kgrp == 0)
        atomicAdd(&rowsum[bcol0 + wn * 32 + ni * 16 + lrow], cs);
    }
  }
}

// ---------------------------------------------------------------------------
// Kernel C: loss = 1/T + mean(log rowsum) - mean(pos)
// ---------------------------------------------------------------------------
__global__ __launch_bounds__(1024) void finalize_kernel(
    const float* __restrict__ rowsum, const float* __restrict__ pos,
    float* __restrict__ out) {
  const int t = threadIdx.x;
  float ls = 0.f, ps = 0.f;
  for (int i = t; i < NROWS; i += 1024) ls += logf(rowsum[i]);
  for (int i = t; i < NPAIR; i += 1024) ps += pos[i];
  #pragma unroll
  for (int off = 32; off; off >>= 1) {
    ls += __shfl_down(ls, off);
    ps += __shfl_down(ps, off);
  }
  __shared__ float sls[16], sps[16];
  const int wave = t >> 6, lane = t & 63;
  if (lane == 0) { sls[wave] = ls; sps[wave] = ps; }
  __syncthreads();
  if (t == 0) {
    float LS = 0.f, PS = 0.f;
    #pragma unroll
    for (int w = 0; w < 16; ++w) { LS += sls[w]; PS += sps[w]; }
    out[0] = INV_T + LS / (float)NROWS - PS / (float)NPAIR;
  }
}

extern "C" void kernel_launch(void* const* d_in, const int* in_sizes, int n_in,
                              void* d_out, int out_size, void* d_ws, size_t ws_size,
                              hipStream_t stream) {
  const float* l1 = (const float*)d_in[0];
  const float* l2 = (const float*)d_in[1];
  float* out = (float*)d_out;

  char* ws = (char*)d_ws;
  unsigned char* Z = (unsigned char*)ws;                   // 8 MB fp8 (k-paired)
  float* rowsum = (float*)(ws + (size_t)NROWS * DIM);      // 32 KB
  float* pos    = rowsum + NROWS;                          // 16 KB

  normalize_kernel<<<NPAIR, 256, 0, stream>>>(l1, l2, Z, pos, rowsum);
  ntxent_gemm_all<<<NOFF + NTAIL, 512, 0, stream>>>(Z, rowsum);
  finalize_kernel<<<1, 1024, 0, stream>>>(rowsum, pos, out);
}